// Round 7
// baseline (470.638 us; speedup 1.0000x reference)
//
#include <hip/hip_runtime.h>
#include <hip/hip_bf16.h>
#include <math.h>

typedef __hip_bfloat16 bf16;
typedef short s8v __attribute__((ext_vector_type(8)));
typedef short s4v __attribute__((ext_vector_type(4)));
typedef float f4v __attribute__((ext_vector_type(4)));

__device__ __forceinline__ float b2f(bf16 x) { return __bfloat162float(x); }
__device__ __forceinline__ bf16 f2b(float x) { return __float2bfloat16(x); }
__device__ __forceinline__ f4v mfma16(s8v a, s8v b, f4v c) {
    return __builtin_amdgcn_mfma_f32_16x16x32_bf16(a, b, c, 0, 0, 0);
}
// async global->LDS, 16B per lane, LDS dst = wave-uniform base + lane*16
__device__ __forceinline__ void async16(const bf16* g, bf16* l) {
    __builtin_amdgcn_global_load_lds(
        (const __attribute__((address_space(1))) void*)g,
        (__attribute__((address_space(3))) void*)l, 16, 0, 0);
}

// Problem constants
constexpr int Bn = 4, Tn = 2048, Dn = 1024, KDn = 512, VDn = 1024;
constexpr int Hn = 4, Mn = 64, HKn = 128, HVn = 256;
constexpr int BT = Bn * Tn; // 8192

// ---------------------------------------------------------------------------
// Dtype probe (fp32 vs bf16 inputs).
// ---------------------------------------------------------------------------
__global__ __launch_bounds__(256) void probe_dtype_kernel(
    const void* __restrict__ x, int* __restrict__ flag)
{
    const bf16* xb = (const bf16*)x;
    float mx = 0.f;
    for (int i = threadIdx.x; i < 4096; i += 256) {
        float v = fabsf(b2f(xb[i]));
        if (isnan(v)) v = 1e30f;
        mx = fmaxf(mx, v);
    }
    __shared__ float red[256];
    red[threadIdx.x] = mx;
    __syncthreads();
    for (int s = 128; s > 0; s >>= 1) {
        if (threadIdx.x < s) red[threadIdx.x] = fmaxf(red[threadIdx.x], red[threadIdx.x + s]);
        __syncthreads();
    }
    if (threadIdx.x == 0) flag[0] = (red[0] > 1e6f) ? 1 : 0;
}

__global__ __launch_bounds__(256) void convert_kernel(
    const void* __restrict__ src, bf16* __restrict__ dst,
    const int* __restrict__ flag, int n)
{
    int is32 = flag[0];
    int i0 = (blockIdx.x * 256 + threadIdx.x) * 4;
#pragma unroll
    for (int j = 0; j < 4; j++) {
        int i = i0 + j;
        if (i < n)
            dst[i] = is32 ? f2b(((const float*)src)[i]) : ((const bf16*)src)[i];
    }
}

// All small 1-D weights in one block: qw(2048) kw(2048) vw(4096) gnw(256)
__global__ __launch_bounds__(256) void convert_small_kernel(
    const void* __restrict__ q, const void* __restrict__ k,
    const void* __restrict__ v, const void* __restrict__ g,
    bf16* __restrict__ qd, bf16* __restrict__ kd,
    bf16* __restrict__ vd, bf16* __restrict__ gd,
    const int* __restrict__ flag)
{
    int is32 = flag[0];
    for (int i = threadIdx.x; i < 8448; i += 256) {
        const void* s; bf16* d; int l;
        if (i < 2048)      { s = q; d = qd; l = i; }
        else if (i < 4096) { s = k; d = kd; l = i - 2048; }
        else if (i < 8192) { s = v; d = vd; l = i - 4096; }
        else               { s = g; d = gd; l = i - 8192; }
        d[l] = is32 ? f2b(((const float*)s)[l]) : ((const bf16*)s)[l];
    }
}

// All six weight transposes in one launch. W[K][N] -> WT[N][K] bf16.
__global__ __launch_bounds__(256) void convert_t6_kernel(
    const void* s0, const void* s1, const void* s2, const void* s3,
    const void* s4, const void* s5,
    bf16* d0, bf16* d1, bf16* d2, bf16* d3, bf16* d4, bf16* d5,
    const int* __restrict__ flag)
{
    __shared__ bf16 tile[64 * 72];
    int is32 = flag[0];
    int nb = blockIdx.x;
    const void* src; bf16* dst; int K, N, loc;
    if (nb < 128)       { src = s0; dst = d0; K = 1024; N = 512;  loc = nb; }
    else if (nb < 256)  { src = s1; dst = d1; K = 1024; N = 512;  loc = nb - 128; }
    else if (nb < 512)  { src = s2; dst = d2; K = 1024; N = 1024; loc = nb - 256; }
    else if (nb < 576)  { src = s3; dst = d3; K = 1024; N = 256;  loc = nb - 512; }
    else if (nb < 832)  { src = s4; dst = d4; K = 1024; N = 1024; loc = nb - 576; }
    else                { src = s5; dst = d5; K = 1024; N = 1024; loc = nb - 832; }
    int nt = N >> 6;
    int n0 = (loc % nt) * 64, k0 = (loc / nt) * 64;
    int tid = threadIdx.x;
    int r = tid >> 2, seg = (tid & 3) * 16;
#pragma unroll
    for (int i = 0; i < 16; i++) {
        size_t gi = (size_t)(k0 + r) * N + n0 + seg + i;
        float v = is32 ? ((const float*)src)[gi] : b2f(((const bf16*)src)[gi]);
        tile[r * 72 + seg + i] = f2b(v);
    }
    __syncthreads();
    bf16 tmp[16];
#pragma unroll
    for (int i = 0; i < 16; i++) tmp[i] = tile[(seg + i) * 72 + r];
    size_t o = (size_t)(n0 + r) * K + k0 + seg;
    *(s8v*)&dst[o] = *(s8v*)&tmp[0];
    *(s8v*)&dst[o + 8] = *(s8v*)&tmp[8];
}

// ---------------------------------------------------------------------------
// MFMA GEMM w/ global_load_lds (m97 recipe): C[M,N] = A[M,K] * BT[N,K]^T.
// 128x128 tile, BK=64, unpadded lane-ordered LDS tiles.
// EP: 0 bf16; 2 exp-clip dual-store (E + ET); 3 dynamic fp32/bf16.
// ---------------------------------------------------------------------------
template <int EP>
__global__ __launch_bounds__(256) void gemm_mfma(
    const bf16* __restrict__ A, const bf16* __restrict__ BT,
    void* __restrict__ Cout, bf16* __restrict__ Cout2,
    const int* __restrict__ flag, int M, int N, int K)
{
    __shared__ bf16 Xs[128 * 64];
    __shared__ bf16 Ws2[128 * 64];
    const int tid = threadIdx.x;
    const int w = tid >> 6, lane = tid & 63;
    const int l16 = lane & 15, q = lane >> 4;
    const int wr = w >> 1, wc = w & 1;
    const int m0 = blockIdx.y * 128, n0 = blockIdx.x * 128;
    int dyn = 0;
    if (EP == 3) dyn = flag[0];

    const int srow = w * 32 + (lane >> 3);
    const int scol = (lane & 7) * 8;
    const bf16* ga = A + (size_t)(m0 + srow) * K + scol;
    const bf16* gb = BT + (size_t)(n0 + srow) * K + scol;

    f4v acc[4][4];
    f4v z = {0.f, 0.f, 0.f, 0.f};
#pragma unroll
    for (int i = 0; i < 4; i++)
#pragma unroll
        for (int j = 0; j < 4; j++) acc[i][j] = z;

    for (int k0 = 0; k0 < K; k0 += 64) {
#pragma unroll
        for (int c = 0; c < 4; c++) {
            async16(ga + (size_t)(c * 8) * K + k0, &Xs[(w * 32 + c * 8) * 64]);
            async16(gb + (size_t)(c * 8) * K + k0, &Ws2[(w * 32 + c * 8) * 64]);
        }
        __syncthreads();
#pragma unroll
        for (int kq = 0; kq < 2; kq++) {
            s8v a[4], b[4];
#pragma unroll
            for (int mi = 0; mi < 4; mi++)
                a[mi] = *(s8v*)&Xs[(wr * 64 + mi * 16 + l16) * 64 + kq * 32 + q * 8];
#pragma unroll
            for (int ni = 0; ni < 4; ni++)
                b[ni] = *(s8v*)&Ws2[(wc * 64 + ni * 16 + l16) * 64 + kq * 32 + q * 8];
#pragma unroll
            for (int mi = 0; mi < 4; mi++)
#pragma unroll
                for (int ni = 0; ni < 4; ni++)
                    acc[mi][ni] = mfma16(a[mi], b[ni], acc[mi][ni]);
        }
        __syncthreads();
    }
#pragma unroll
    for (int mi = 0; mi < 4; mi++)
#pragma unroll
        for (int ni = 0; ni < 4; ni++)
#pragma unroll
            for (int r = 0; r < 4; r++) {
                int row = m0 + wr * 64 + mi * 16 + q * 4 + r;
                int col = n0 + wc * 64 + ni * 16 + l16;
                size_t idx = (size_t)row * N + col;
                float v = acc[mi][ni][r];
                if (EP == 2) {
                    float cl = fminf(32.f, fmaxf(-32.f, v));
                    bf16 e = f2b(expf(cl));
                    ((bf16*)Cout)[idx] = e;
                    int b_ = row >> 11, t_ = row & 2047;
                    int h_ = col >> 6, m_ = col & 63;
                    Cout2[((size_t)((b_ * 4 + h_) * 64 + m_)) * 2048 + t_] = e;
                } else if (EP == 3) {
                    if (dyn) ((float*)Cout)[idx] = v;
                    else ((bf16*)Cout)[idx] = f2b(v);
                } else {
                    ((bf16*)Cout)[idx] = f2b(v);
                }
            }
}

// ---------------------------------------------------------------------------
// Depthwise causal conv (KS=4) + SiLU + RoPE for q AND k in one launch.
// pre row stride 1024 (merged q|k GEMM output).
// ---------------------------------------------------------------------------
__global__ __launch_bounds__(256) void conv_qk_rope_kernel(
    const bf16* __restrict__ pre, const bf16* __restrict__ qw,
    const bf16* __restrict__ kw, bf16* __restrict__ Qo, bf16* __restrict__ Ko)
{
    int gid = blockIdx.x * 256 + threadIdx.x;  // 2 * B*T*H*64
    int sel = gid >> 21;                       // 0 = q, 1 = k
    int g2 = gid & ((1 << 21) - 1);
    const bf16* w = sel ? kw : qw;
    bf16* out = sel ? Ko : Qo;
    int coff = sel ? 512 : 0;
    int d = g2 & 63;
    int h = (g2 >> 6) & 3;
    int t = (g2 >> 8) & 2047;
    int b = g2 >> 19;
    int clo = h * HKn + d, chi = clo + 64;
    float ylo = 0.f, yhi = 0.f;
#pragma unroll
    for (int j = 0; j < 4; j++) {
        int tt = t - 3 + j;
        if (tt >= 0) {
            size_t rb = (size_t)(b * Tn + tt) * 1024 + coff;
            ylo += b2f(pre[rb + clo]) * b2f(w[clo * 4 + j]);
            yhi += b2f(pre[rb + chi]) * b2f(w[chi * 4 + j]);
        }
    }
    ylo = ylo / (1.f + expf(-ylo));
    yhi = yhi / (1.f + expf(-yhi));
    float invf = powf(10000.f, -(float)d * (1.f / 64.f));
    float th = (float)t * invf;
    float c = cosf(th), s = sinf(th);
    size_t rowbase = (size_t)(b * Tn + t) * KDn;
    out[rowbase + clo] = f2b(ylo * c - yhi * s);
    out[rowbase + chi] = f2b(yhi * c + ylo * s);
}

// ---------------------------------------------------------------------------
// conv + silu for v, writing V TRANSPOSED: VT[b*1024 + c][t]. 64x64 tiles.
// ---------------------------------------------------------------------------
__global__ __launch_bounds__(256) void conv_v_t_kernel(
    const bf16* __restrict__ pre, const bf16* __restrict__ w,
    bf16* __restrict__ VT)
{
    __shared__ bf16 tile[64 * 72];
    int c0 = blockIdx.x * 64, t0 = blockIdx.y * 64, b = blockIdx.z;
    int tid = threadIdx.x;
    int row = tid >> 2, seg = (tid & 3) * 16;
    float y[16];
#pragma unroll
    for (int i = 0; i < 16; i++) y[i] = 0.f;
#pragma unroll
    for (int j = 0; j < 4; j++) {
        int tt = t0 + row - 3 + j;
        if (tt >= 0) {
            const bf16* p = &pre[(size_t)(b * Tn + tt) * VDn + c0 + seg];
#pragma unroll
            for (int i = 0; i < 16; i++)
                y[i] += b2f(p[i]) * b2f(w[(c0 + seg + i) * 4 + j]);
        }
    }
#pragma unroll
    for (int i = 0; i < 16; i++) {
        float v = y[i] / (1.f + expf(-y[i]));
        tile[row * 72 + seg + i] = f2b(v);
    }
    __syncthreads();
    bf16 tmp[16];
#pragma unroll
    for (int i = 0; i < 16; i++) tmp[i] = tile[(seg + i) * 72 + row];
    size_t o = (size_t)(b * 1024 + c0 + row) * 2048 + t0 + seg;
    *(s8v*)&VT[o] = *(s8v*)&tmp[0];
    *(s8v*)&VT[o + 8] = *(s8v*)&tmp[8];
}

// ---------------------------------------------------------------------------
// cumsum over tau per (b,h,m) row of ET; wave-parallel scan. C fp32 [b][t][hm].
// ---------------------------------------------------------------------------
__global__ __launch_bounds__(256) void cumsum_kernel(
    const bf16* __restrict__ ET, float* __restrict__ C)
{
    int row = blockIdx.x * 4 + (threadIdx.x >> 6);   // 1024 rows
    int lane = threadIdx.x & 63;
    int b = row >> 8, hm = row & 255;
    const bf16* src = ET + (size_t)row * 2048;
    float run = 0.f;
    for (int ch = 0; ch < 32; ch++) {
        float v = b2f(src[ch * 64 + lane]);
#pragma unroll
        for (int off = 1; off < 64; off <<= 1) {
            float o = __shfl_up(v, off, 64);
            if (lane >= off) v += o;
        }
        C[(size_t)(b * 2048 + ch * 64 + lane) * 256 + hm] = run + v;
        run += __shfl(v, 63, 64);
    }
}

// ---------------------------------------------------------------------------
// attn1: paired t-tiles (31-j, j), double-buffered Kl/Sl, ONE barrier/iter.
// S^T = K Q^T -> Sl; okT += ET * S^T; softmax -> U. grid (bh=16, j=16).
// ---------------------------------------------------------------------------
__global__ __launch_bounds__(256) void attn1_mfma(
    const bf16* __restrict__ Q, const bf16* __restrict__ K,
    const bf16* __restrict__ ET, const float* __restrict__ C,
    bf16* __restrict__ U)
{
    __shared__ bf16 Kl[2][64 * 136];
    __shared__ bf16 Sl[2][64 * 72];
    __shared__ float okT[64 * 65];
    const int tid = threadIdx.x;
    const int w = tid >> 6, lane = tid & 63;
    const int l16 = lane & 15, q = lane >> 4;
    const int b = blockIdx.x >> 2, h = blockIdx.x & 3;
    f4v z = {0.f, 0.f, 0.f, 0.f};
    const int krow[4] = {tid >> 4, (256 + tid) >> 4, (512 + tid) >> 4, (768 + tid) >> 4};
    const int kcol = (tid & 15) * 8;
    const bf16* kbase = K + (size_t)b * Tn * KDn + h * HKn;
    const bf16* etrow = ET + (size_t)((b * 4 + h) * 64 + w * 16 + l16) * 2048;

    for (int half = 0; half < 2; half++) {
        const int t0 = (half == 0 ? (31 - (int)blockIdx.y) : (int)blockIdx.y) * 64;
        const int nIter = t0 / 64 + 1;
        const bf16* qrow = Q + (size_t)(b * Tn + t0 + w * 16 + l16) * KDn + h * HKn;
        s8v qa[4];
#pragma unroll
        for (int kc = 0; kc < 4; kc++) qa[kc] = *(const s8v*)(qrow + kc * 32 + q * 8);
        f4v ok[4];
#pragma unroll
        for (int i = 0; i < 4; i++) ok[i] = z;
        s8v kreg[4];
#pragma unroll
        for (int c = 0; c < 4; c++)
            kreg[c] = *(const s8v*)(kbase + (size_t)krow[c] * KDn + kcol);
        __syncthreads();          // prev-half users of Kl/Sl/okT done
#pragma unroll
        for (int c = 0; c < 4; c++)
            *(s8v*)&Kl[0][krow[c] * 136 + kcol] = kreg[c];
        if (nIter > 1)
#pragma unroll
            for (int c = 0; c < 4; c++)
                kreg[c] = *(const s8v*)(kbase + (size_t)(64 + krow[c]) * KDn + kcol);
        __syncthreads();          // Kl[0] ready
        for (int i = 0; i < nIter; i++) {
            const int tau0 = i * 64;
            const int cur = i & 1, nxt = cur ^ 1;
            s8v ea[2];
#pragma unroll
            for (int kc = 0; kc < 2; kc++)
                ea[kc] = *(const s8v*)(etrow + tau0 + kc * 32 + q * 8);
            f4v sT[4];
#pragma unroll
            for (int fi = 0; fi < 4; fi++) sT[fi] = z;
#pragma unroll
            for (int kc = 0; kc < 4; kc++)
#pragma unroll
                for (int fi = 0; fi < 4; fi++) {
                    s8v kb = *(s8v*)&Kl[cur][(fi * 16 + l16) * 136 + kc * 32 + q * 8];
                    sT[fi] = mfma16(kb, qa[kc], sT[fi]);
                }
            const int tl = w * 16 + l16;
#pragma unroll
            for (int fi = 0; fi < 4; fi++) {
                alignas(8) bf16 pk[4];
#pragma unroll
                for (int r = 0; r < 4; r++) {
                    int taul = fi * 16 + q * 4 + r;
                    float v = sT[fi][r] * 0.08838834764831845f;
                    pk[r] = ((tau0 + taul) <= (t0 + tl)) ? f2b(v) : f2b(0.f);
                }
                *(s4v*)&Sl[cur][tl * 72 + fi * 16 + q * 4] = *(s4v*)pk;
            }
            if (i + 1 < nIter) {
#pragma unroll
                for (int c = 0; c < 4; c++)
                    *(s8v*)&Kl[nxt][krow[c] * 136 + kcol] = kreg[c];
                if (i + 2 < nIter)
#pragma unroll
                    for (int c = 0; c < 4; c++)
                        kreg[c] = *(const s8v*)(kbase + (size_t)((i + 2) * 64 + krow[c]) * KDn + kcol);
            }
            __syncthreads();      // Sl[cur] + Kl[nxt] ready
#pragma unroll
            for (int kc = 0; kc < 2; kc++)
#pragma unroll
                for (int tf = 0; tf < 4; tf++) {
                    s8v sb = *(s8v*)&Sl[cur][(tf * 16 + l16) * 72 + kc * 32 + q * 8];
                    ok[tf] = mfma16(ea[kc], sb, ok[tf]);
                }
        }
        __syncthreads();
#pragma unroll
        for (int tf = 0; tf < 4; tf++)
#pragma unroll
            for (int r = 0; r < 4; r++)
                okT[(w * 16 + q * 4 + r) * 65 + tf * 16 + l16] = ok[tf][r];
        __syncthreads();
        if (tid < 64) {
            int t = tid;
            size_t base = (size_t)(b * Tn + t0 + t) * 256 + h * 64;
            float mx = -1e30f;
            for (int m = 0; m < 64; m++) {
                float v = okT[m * 65 + t] / C[base + m];
                okT[m * 65 + t] = v;
                mx = fmaxf(mx, v);
            }
            float sum = 0.f;
            for (int m = 0; m < 64; m++) {
                float e = expf(okT[m * 65 + t] - mx);
                okT[m * 65 + t] = e;
                sum += e;
            }
            float inv = 1.f / sum;
            for (int m = 0; m < 64; m++)
                U[base + m] = f2b(okT[m * 65 + t] * inv / C[base + m]);
        }
    }
}

// ---------------------------------------------------------------------------
// attn2: paired t-tiles, double-buffered El/Pl, ONE barrier/iter.
// P^T = E U^T -> Pl; O^T += VT * P^T; fused RMSNorm*gn*silu(G) epilogue
// (shuffle reduction, no atomics). grid (bh=16, j=16).
// ---------------------------------------------------------------------------
__global__ __launch_bounds__(256) void attn2_mfma(
    const bf16* __restrict__ U, const bf16* __restrict__ E,
    const bf16* __restrict__ VT, const bf16* __restrict__ G,
    const bf16* __restrict__ gn, bf16* __restrict__ OV)
{
    __shared__ bf16 El[2][64 * 72];
    __shared__ bf16 Pl[2][64 * 72];
    __shared__ float Ot[64 * 260];
    __shared__ float swave[4][64];
    __shared__ float ssum[64];
    const int tid = threadIdx.x;
    const int w = tid >> 6, lane = tid & 63;
    const int l16 = lane & 15, q = lane >> 4;
    const int b = blockIdx.x >> 2, h = blockIdx.x & 3;
    f4v z = {0.f, 0.f, 0.f, 0.f};
    const int erow[2] = {tid >> 3, (256 + tid) >> 3};
    const int ecol = (tid & 7) * 8;
    const bf16* ebase = E + (size_t)b * Tn * 256 + h * 64;
    const bf16* vtbase = VT + (size_t)(b * 1024 + h * 256 + w * 16 + l16) * 2048;

    for (int half = 0; half < 2; half++) {
        const int t0 = (half == 0 ? (31 - (int)blockIdx.y) : (int)blockIdx.y) * 64;
        const int nIter = t0 / 64 + 1;
        const bf16* urow = U + (size_t)(b * Tn + t0 + w * 16 + l16) * 256 + h * 64;
        s8v ua[2];
#pragma unroll
        for (int kc = 0; kc < 2; kc++) ua[kc] = *(const s8v*)(urow + kc * 32 + q * 8);
        f4v oacc[4][4];
#pragma unroll
        for (int zc = 0; zc < 4; zc++)
#pragma unroll
            for (int i = 0; i < 4; i++) oacc[zc][i] = z;
        s8v ereg[2];
#pragma unroll
        for (int c = 0; c < 2; c++)
            ereg[c] = *(const s8v*)(ebase + (size_t)erow[c] * 256 + ecol);
        __syncthreads();          // prev-half users of El/Pl/Ot/swave/ssum done
#pragma unroll
        for (int c = 0; c < 2; c++)
            *(s8v*)&El[0][erow[c] * 72 + ecol] = ereg[c];
        if (nIter > 1)
#pragma unroll
            for (int c = 0; c < 2; c++)
                ereg[c] = *(const s8v*)(ebase + (size_t)(64 + erow[c]) * 256 + ecol);
        __syncthreads();          // El[0] ready
        for (int i = 0; i < nIter; i++) {
            const int tau0 = i * 64;
            const int cur = i & 1, nxt = cur ^ 1;
            s8v vt[4][2];
#pragma unroll
            for (int zc = 0; zc < 4; zc++)
#pragma unroll
                for (int kc = 0; kc < 2; kc++)
                    vt[zc][kc] = *(const s8v*)(vtbase + (size_t)(zc * 64) * 2048
                                               + tau0 + kc * 32 + q * 8);
            f4v pT[4];
#pragma unroll
            for (int fi = 0; fi < 4; fi++) pT[fi] = z;
#pragma unroll
            for (int kc = 0; kc < 2; kc++)
#pragma unroll
                for (int fi = 0; fi < 4; fi++) {
                    s8v eb = *(s8v*)&El[cur][(fi * 16 + l16) * 72 + kc * 32 + q * 8];
                    pT[fi] = mfma16(eb, ua[kc], pT[fi]);
                }
            const int tl = w * 16 + l16;
#pragma unroll
            for (int fi = 0; fi < 4; fi++) {
                alignas(8) bf16 pk[4];
#pragma unroll
                for (int r = 0; r < 4; r++) {
                    int taul = fi * 16 + q * 4 + r;
                    pk[r] = ((tau0 + taul) <= (t0 + tl)) ? f2b(pT[fi][r]) : f2b(0.f);
                }
                *(s4v*)&Pl[cur][tl * 72 + fi * 16 + q * 4] = *(s4v*)pk;
            }
            if (i + 1 < nIter) {
#pragma unroll
                for (int c = 0; c < 2; c++)
                    *(s8v*)&El[nxt][erow[c] * 72 + ecol] = ereg[c];
                if (i + 2 < nIter)
#pragma unroll
                    for (int c = 0; c < 2; c++)
                        ereg[c] = *(const s8v*)(ebase + (size_t)((i + 2) * 64 + erow[c]) * 256 + ecol);
            }
            __syncthreads();      // Pl[cur] + El[nxt] ready
            s8v pb[2][4];
#pragma unroll
            for (int kc = 0; kc < 2; kc++)
#pragma unroll
                for (int tf = 0; tf < 4; tf++)
                    pb[kc][tf] = *(s8v*)&Pl[cur][(tf * 16 + l16) * 72 + kc * 32 + q * 8];
#pragma unroll
            for (int zc = 0; zc < 4; zc++)
#pragma unroll
                for (int kc = 0; kc < 2; kc++)
#pragma unroll
                    for (int tf = 0; tf < 4; tf++)
                        oacc[zc][tf] = mfma16(vt[zc][kc], pb[kc][tf], oacc[zc][tf]);
        }
        // ---- epilogue: shuffle-reduced sum of squares + fused norm*gate ----
        float part[4] = {0.f, 0.f, 0.f, 0.f};
#pragma unroll
        for (int zc = 0; zc < 4; zc++)
#pragma unroll
            for (int tf = 0; tf < 4; tf++)
#pragma unroll
                for (int r = 0; r < 4; r++)
                    part[tf] += oacc[zc][tf][r] * oacc[zc][tf][r];
#pragma unroll
        for (int tf = 0; tf < 4; tf++) {
            part[tf] += __shfl_xor(part[tf], 16, 64);
            part[tf] += __shfl_xor(part[tf], 32, 64);
        }
        if (q == 0) {
#pragma unroll
            for (int tf = 0; tf < 4; tf++) swave[w][tf * 16 + l16] = part[tf];
        }
        // deposit O^T -> Ot[t][v] (f4v, rows pitch 260)
#pragma unroll
        for (int zc = 0; zc < 4; zc++)
#pragma unroll
            for (int tf = 0; tf < 4; tf++)
                *(f4v*)&Ot[(tf * 16 + l16) * 260 + zc * 64 + w * 16 + q * 4] = oacc[zc][tf];
        __syncthreads();          // Ot + swave ready
        if (tid < 64)
            ssum[tid] = rsqrtf((swave[0][tid] + swave[1][tid] + swave[2][tid] + swave[3][tid])
                               * (1.0f / 256.0f) + 1e-5f);
        __syncthreads();          // ssum ready
        const int trow = tid >> 2, vs = (tid & 3) * 64;
        float rs = ssum[trow];
        size_t orow = (size_t)(b * Tn + t0 + trow) * VDn + h * HVn + vs;
#pragma unroll
        for (int j = 0; j < 4; j++) {
            int vo = vs + j * 16;
            alignas(16) bf16 gh[16];
            *(s8v*)&gh[0] = *(const s8v*)&G[orow + j * 16];
            *(s8v*)&gh[8] = *(const s8v*)&G[orow + j * 16 + 8];
            alignas(16) bf16 tmp[16];
#pragma unroll
            for (int i = 0; i < 16; i++) {
                float g = b2f(gh[i]);
                float sg = g / (1.f + expf(-g));
                float val = Ot[trow * 260 + vo + i] * rs * b2f(gn[vo + i]) * sg;
                tmp[i] = f2b(val);
            }
            *(s8v*)&OV[orow + j * 16] = *(s8v*)&tmp[0];
            *(s8v*)&OV[orow + j * 16 + 8] = *(s8v*)&tmp[8];
        }
        // next-half prologue barrier protects Ot/ssum/swave/El/Pl reuse
    }
}

// ---------------------------------------------------------------------------
extern "C" void kernel_launch(void* const* d_in, const int* in_sizes, int n_in,
                              void* d_out, int out_size, void* d_ws, size_t ws_size,
                              hipStream_t stream)
{
    constexpr size_t MB = 1u << 20;
    char* w = (char*)d_ws;
    bf16* Xb   = (bf16*)(w + 0);                 // [0,16)  ; later OV
    bf16* OVb  = (bf16*)(w + 0);
    bf16* WoT  = (bf16*)(w + 16 * MB);           // [16,18)
    bf16* WgT  = (bf16*)(w + 18 * MB);           // [18,20)
    bf16* WqT  = (bf16*)(w + 20 * MB);           // [20,21)  (WkT contiguous after)
    bf16* WkT  = (bf16*)(w + 21 * MB);           // [21,22)
    bf16* WvT  = (bf16*)(w + 22 * MB);           // [22,24)
    bf16* WsT  = (bf16*)(w + 24 * MB);           // [24,24.5)
    bf16* gnwb = (bf16*)(w + 24 * MB + 524288);  // smalls in [24.5,25)
    bf16* qwb  = (bf16*)(w + 24 * MB + 532480);
    bf16* kwb  = (bf16*)(w + 24 * MB + 540672);
    bf16* vwb  = (bf16*)(w + 24 * MB + 548864);
    int*  flagp= (int*) (w + 24 * MB + 565248);
    bf16* Qb   = (bf16*)(w + 25 * MB);           // [25,33) ; later ghat [25,41)
    bf16* Kb   = (bf16*)(w + 33 * MB);           // [33,41)
    bf16* ghat = (bf16*)(w + 25 * MB);
    bf16* qkpre= (bf16*)(w + 41 * MB);           // [41,57) ; later E/ET/C
    bf16* vpre = (bf16*)(w + 41 * MB);
    bf16* Ebuf = (bf16*)(w + 41 * MB);           // [41,45)
    bf16* ETb  = (bf16*)(w + 45 * MB);           // [45,49)
    float* Cbuf= (float*)(w + 49 * MB);          // [49,57)
    bf16* Ubuf = (bf16*)(w + 57 * MB);           // [57,61)
    bf16* VT   = (bf16*)d_out;                   // V^T staged in d_out

    dim3 blk(256);
    probe_dtype_kernel<<<1, blk, 0, stream>>>(d_in[0], flagp);
    convert_kernel<<<16384, blk, 0, stream>>>(d_in[0], Xb, flagp, BT * Dn);
    convert_small_kernel<<<1, blk, 0, stream>>>(d_in[7], d_in[8], d_in[9], d_in[10],
                                                qwb, kwb, vwb, gnwb, flagp);
    convert_t6_kernel<<<1088, blk, 0, stream>>>(d_in[1], d_in[2], d_in[3], d_in[4],
                                                d_in[5], d_in[6],
                                                WqT, WkT, WvT, WsT, WgT, WoT, flagp);
    // merged q|k projection (N=1024: cols 0..511 q, 512..1023 k)
    gemm_mfma<0><<<dim3(8, 64), blk, 0, stream>>>(Xb, WqT, qkpre, nullptr, flagp, BT, 1024, Dn);
    conv_qk_rope_kernel<<<16384, blk, 0, stream>>>(qkpre, qwb, kwb, Qb, Kb);
    // v projection + transpose conv (vpre overwrites dead qkpre)
    gemm_mfma<0><<<dim3(8, 64), blk, 0, stream>>>(Xb, WvT, vpre, nullptr, flagp, BT, VDn, Dn);
    conv_v_t_kernel<<<dim3(16, 32, 4), blk, 0, stream>>>(vpre, vwb, VT);
    // slot gates: E (and ET) = exp(clip(X@Ws)); C = cumsum(ET)
    gemm_mfma<2><<<dim3(2, 64), blk, 0, stream>>>(Xb, WsT, Ebuf, ETb, flagp, BT, 256, Dn);
    cumsum_kernel<<<256, blk, 0, stream>>>(ETb, Cbuf);
    // attn1 -> U (paired tiles, 1 barrier/iter)
    attn1_mfma<<<dim3(16, 16), blk, 0, stream>>>(Qb, Kb, ETb, Cbuf, Ubuf);
    // gate projection into dead Qb/Kb region
    gemm_mfma<0><<<dim3(8, 64), blk, 0, stream>>>(Xb, WgT, ghat, nullptr, flagp, BT, VDn, Dn);
    // attn2 with fused norm/gate -> OV (over dead Xb)
    attn2_mfma<<<dim3(16, 16), blk, 0, stream>>>(Ubuf, Ebuf, VT, ghat, gnwb, OVb);
    // output projection
    gemm_mfma<3><<<dim3(8, 64), blk, 0, stream>>>(OVb, WoT, d_out, nullptr, flagp, BT, Dn, VDn);
}

// Round 8
// 452.108 us; speedup vs baseline: 1.0410x; 1.0410x over previous
//
#include <hip/hip_runtime.h>
#include <hip/hip_bf16.h>
#include <math.h>

typedef __hip_bfloat16 bf16;
typedef short s8v __attribute__((ext_vector_type(8)));
typedef short s4v __attribute__((ext_vector_type(4)));
typedef float f4v __attribute__((ext_vector_type(4)));

__device__ __forceinline__ float b2f(bf16 x) { return __bfloat162float(x); }
__device__ __forceinline__ bf16 f2b(float x) { return __float2bfloat16(x); }
__device__ __forceinline__ f4v mfma16(s8v a, s8v b, f4v c) {
    return __builtin_amdgcn_mfma_f32_16x16x32_bf16(a, b, c, 0, 0, 0);
}
// async global->LDS, 16B per lane, LDS dst = wave-uniform base + lane*16
__device__ __forceinline__ void async16(const bf16* g, bf16* l) {
    __builtin_amdgcn_global_load_lds(
        (const __attribute__((address_space(1))) void*)g,
        (__attribute__((address_space(3))) void*)l, 16, 0, 0);
}

// Problem constants
constexpr int Bn = 4, Tn = 2048, Dn = 1024, KDn = 512, VDn = 1024;
constexpr int Hn = 4, Mn = 64, HKn = 128, HVn = 256;
constexpr int BT = Bn * Tn; // 8192

// ---------------------------------------------------------------------------
// Dtype probe (fp32 vs bf16 inputs).
// ---------------------------------------------------------------------------
__global__ __launch_bounds__(256) void probe_dtype_kernel(
    const void* __restrict__ x, int* __restrict__ flag)
{
    const bf16* xb = (const bf16*)x;
    float mx = 0.f;
    for (int i = threadIdx.x; i < 4096; i += 256) {
        float v = fabsf(b2f(xb[i]));
        if (isnan(v)) v = 1e30f;
        mx = fmaxf(mx, v);
    }
    __shared__ float red[256];
    red[threadIdx.x] = mx;
    __syncthreads();
    for (int s = 128; s > 0; s >>= 1) {
        if (threadIdx.x < s) red[threadIdx.x] = fmaxf(red[threadIdx.x], red[threadIdx.x + s]);
        __syncthreads();
    }
    if (threadIdx.x == 0) flag[0] = (red[0] > 1e6f) ? 1 : 0;
}

__global__ __launch_bounds__(256) void convert_kernel(
    const void* __restrict__ src, bf16* __restrict__ dst,
    const int* __restrict__ flag, int n)
{
    int is32 = flag[0];
    int i0 = (blockIdx.x * 256 + threadIdx.x) * 4;
#pragma unroll
    for (int j = 0; j < 4; j++) {
        int i = i0 + j;
        if (i < n)
            dst[i] = is32 ? f2b(((const float*)src)[i]) : ((const bf16*)src)[i];
    }
}

// All small 1-D weights in one block: qw(2048) kw(2048) vw(4096) gnw(256)
__global__ __launch_bounds__(256) void convert_small_kernel(
    const void* __restrict__ q, const void* __restrict__ k,
    const void* __restrict__ v, const void* __restrict__ g,
    bf16* __restrict__ qd, bf16* __restrict__ kd,
    bf16* __restrict__ vd, bf16* __restrict__ gd,
    const int* __restrict__ flag)
{
    int is32 = flag[0];
    for (int i = threadIdx.x; i < 8448; i += 256) {
        const void* s; bf16* d; int l;
        if (i < 2048)      { s = q; d = qd; l = i; }
        else if (i < 4096) { s = k; d = kd; l = i - 2048; }
        else if (i < 8192) { s = v; d = vd; l = i - 4096; }
        else               { s = g; d = gd; l = i - 8192; }
        d[l] = is32 ? f2b(((const float*)s)[l]) : ((const bf16*)s)[l];
    }
}

// All six weight transposes in one launch. W[K][N] -> WT[N][K] bf16.
__global__ __launch_bounds__(256) void convert_t6_kernel(
    const void* s0, const void* s1, const void* s2, const void* s3,
    const void* s4, const void* s5,
    bf16* d0, bf16* d1, bf16* d2, bf16* d3, bf16* d4, bf16* d5,
    const int* __restrict__ flag)
{
    __shared__ bf16 tile[64 * 72];
    int is32 = flag[0];
    int nb = blockIdx.x;
    const void* src; bf16* dst; int K, N, loc;
    if (nb < 128)       { src = s0; dst = d0; K = 1024; N = 512;  loc = nb; }
    else if (nb < 256)  { src = s1; dst = d1; K = 1024; N = 512;  loc = nb - 128; }
    else if (nb < 512)  { src = s2; dst = d2; K = 1024; N = 1024; loc = nb - 256; }
    else if (nb < 576)  { src = s3; dst = d3; K = 1024; N = 256;  loc = nb - 512; }
    else if (nb < 832)  { src = s4; dst = d4; K = 1024; N = 1024; loc = nb - 576; }
    else                { src = s5; dst = d5; K = 1024; N = 1024; loc = nb - 832; }
    int nt = N >> 6;
    int n0 = (loc % nt) * 64, k0 = (loc / nt) * 64;
    int tid = threadIdx.x;
    int r = tid >> 2, seg = (tid & 3) * 16;
#pragma unroll
    for (int i = 0; i < 16; i++) {
        size_t gi = (size_t)(k0 + r) * N + n0 + seg + i;
        float v = is32 ? ((const float*)src)[gi] : b2f(((const bf16*)src)[gi]);
        tile[r * 72 + seg + i] = f2b(v);
    }
    __syncthreads();
    bf16 tmp[16];
#pragma unroll
    for (int i = 0; i < 16; i++) tmp[i] = tile[(seg + i) * 72 + r];
    size_t o = (size_t)(n0 + r) * K + k0 + seg;
    *(s8v*)&dst[o] = *(s8v*)&tmp[0];
    *(s8v*)&dst[o + 8] = *(s8v*)&tmp[8];
}

// ---------------------------------------------------------------------------
// MFMA GEMM w/ global_load_lds (m97 recipe): C[M,N] = A[M,K] * BT[N,K]^T.
// 128x128 tile, BK=64, unpadded lane-ordered LDS tiles.
// EP: 0 bf16; 2 exp-clip dual-store (E + ET); 3 dynamic fp32/bf16.
// ---------------------------------------------------------------------------
template <int EP>
__global__ __launch_bounds__(256) void gemm_mfma(
    const bf16* __restrict__ A, const bf16* __restrict__ BT,
    void* __restrict__ Cout, bf16* __restrict__ Cout2,
    const int* __restrict__ flag, int M, int N, int K)
{
    __shared__ bf16 Xs[128 * 64];
    __shared__ bf16 Ws2[128 * 64];
    const int tid = threadIdx.x;
    const int w = tid >> 6, lane = tid & 63;
    const int l16 = lane & 15, q = lane >> 4;
    const int wr = w >> 1, wc = w & 1;
    const int m0 = blockIdx.y * 128, n0 = blockIdx.x * 128;
    int dyn = 0;
    if (EP == 3) dyn = flag[0];

    const int srow = w * 32 + (lane >> 3);
    const int scol = (lane & 7) * 8;
    const bf16* ga = A + (size_t)(m0 + srow) * K + scol;
    const bf16* gb = BT + (size_t)(n0 + srow) * K + scol;

    f4v acc[4][4];
    f4v z = {0.f, 0.f, 0.f, 0.f};
#pragma unroll
    for (int i = 0; i < 4; i++)
#pragma unroll
        for (int j = 0; j < 4; j++) acc[i][j] = z;

    for (int k0 = 0; k0 < K; k0 += 64) {
#pragma unroll
        for (int c = 0; c < 4; c++) {
            async16(ga + (size_t)(c * 8) * K + k0, &Xs[(w * 32 + c * 8) * 64]);
            async16(gb + (size_t)(c * 8) * K + k0, &Ws2[(w * 32 + c * 8) * 64]);
        }
        __syncthreads();
#pragma unroll
        for (int kq = 0; kq < 2; kq++) {
            s8v a[4], b[4];
#pragma unroll
            for (int mi = 0; mi < 4; mi++)
                a[mi] = *(s8v*)&Xs[(wr * 64 + mi * 16 + l16) * 64 + kq * 32 + q * 8];
#pragma unroll
            for (int ni = 0; ni < 4; ni++)
                b[ni] = *(s8v*)&Ws2[(wc * 64 + ni * 16 + l16) * 64 + kq * 32 + q * 8];
#pragma unroll
            for (int mi = 0; mi < 4; mi++)
#pragma unroll
                for (int ni = 0; ni < 4; ni++)
                    acc[mi][ni] = mfma16(a[mi], b[ni], acc[mi][ni]);
        }
        __syncthreads();
    }
#pragma unroll
    for (int mi = 0; mi < 4; mi++)
#pragma unroll
        for (int ni = 0; ni < 4; ni++)
#pragma unroll
            for (int r = 0; r < 4; r++) {
                int row = m0 + wr * 64 + mi * 16 + q * 4 + r;
                int col = n0 + wc * 64 + ni * 16 + l16;
                size_t idx = (size_t)row * N + col;
                float v = acc[mi][ni][r];
                if (EP == 2) {
                    float cl = fminf(32.f, fmaxf(-32.f, v));
                    bf16 e = f2b(expf(cl));
                    ((bf16*)Cout)[idx] = e;
                    int b_ = row >> 11, t_ = row & 2047;
                    int h_ = col >> 6, m_ = col & 63;
                    Cout2[((size_t)((b_ * 4 + h_) * 64 + m_)) * 2048 + t_] = e;
                } else if (EP == 3) {
                    if (dyn) ((float*)Cout)[idx] = v;
                    else ((bf16*)Cout)[idx] = f2b(v);
                } else {
                    ((bf16*)Cout)[idx] = f2b(v);
                }
            }
}

// ---------------------------------------------------------------------------
// Depthwise causal conv (KS=4) + SiLU + RoPE for q AND k in one launch.
// pre row stride 1024 (merged q|k GEMM output).
// ---------------------------------------------------------------------------
__global__ __launch_bounds__(256) void conv_qk_rope_kernel(
    const bf16* __restrict__ pre, const bf16* __restrict__ qw,
    const bf16* __restrict__ kw, bf16* __restrict__ Qo, bf16* __restrict__ Ko)
{
    int gid = blockIdx.x * 256 + threadIdx.x;  // 2 * B*T*H*64
    int sel = gid >> 21;                       // 0 = q, 1 = k
    int g2 = gid & ((1 << 21) - 1);
    const bf16* w = sel ? kw : qw;
    bf16* out = sel ? Ko : Qo;
    int coff = sel ? 512 : 0;
    int d = g2 & 63;
    int h = (g2 >> 6) & 3;
    int t = (g2 >> 8) & 2047;
    int b = g2 >> 19;
    int clo = h * HKn + d, chi = clo + 64;
    float ylo = 0.f, yhi = 0.f;
#pragma unroll
    for (int j = 0; j < 4; j++) {
        int tt = t - 3 + j;
        if (tt >= 0) {
            size_t rb = (size_t)(b * Tn + tt) * 1024 + coff;
            ylo += b2f(pre[rb + clo]) * b2f(w[clo * 4 + j]);
            yhi += b2f(pre[rb + chi]) * b2f(w[chi * 4 + j]);
        }
    }
    ylo = ylo / (1.f + expf(-ylo));
    yhi = yhi / (1.f + expf(-yhi));
    float invf = powf(10000.f, -(float)d * (1.f / 64.f));
    float th = (float)t * invf;
    float c = cosf(th), s = sinf(th);
    size_t rowbase = (size_t)(b * Tn + t) * KDn;
    out[rowbase + clo] = f2b(ylo * c - yhi * s);
    out[rowbase + chi] = f2b(yhi * c + ylo * s);
}

// ---------------------------------------------------------------------------
// conv + silu for v, writing V TRANSPOSED: VT[b*1024 + c][t]. 64x64 tiles.
// ---------------------------------------------------------------------------
__global__ __launch_bounds__(256) void conv_v_t_kernel(
    const bf16* __restrict__ pre, const bf16* __restrict__ w,
    bf16* __restrict__ VT)
{
    __shared__ bf16 tile[64 * 72];
    int c0 = blockIdx.x * 64, t0 = blockIdx.y * 64, b = blockIdx.z;
    int tid = threadIdx.x;
    int row = tid >> 2, seg = (tid & 3) * 16;
    float y[16];
#pragma unroll
    for (int i = 0; i < 16; i++) y[i] = 0.f;
#pragma unroll
    for (int j = 0; j < 4; j++) {
        int tt = t0 + row - 3 + j;
        if (tt >= 0) {
            const bf16* p = &pre[(size_t)(b * Tn + tt) * VDn + c0 + seg];
#pragma unroll
            for (int i = 0; i < 16; i++)
                y[i] += b2f(p[i]) * b2f(w[(c0 + seg + i) * 4 + j]);
        }
    }
#pragma unroll
    for (int i = 0; i < 16; i++) {
        float v = y[i] / (1.f + expf(-y[i]));
        tile[row * 72 + seg + i] = f2b(v);
    }
    __syncthreads();
    bf16 tmp[16];
#pragma unroll
    for (int i = 0; i < 16; i++) tmp[i] = tile[(seg + i) * 72 + row];
    size_t o = (size_t)(b * 1024 + c0 + row) * 2048 + t0 + seg;
    *(s8v*)&VT[o] = *(s8v*)&tmp[0];
    *(s8v*)&VT[o + 8] = *(s8v*)&tmp[8];
}

// ---------------------------------------------------------------------------
// cumsum over tau per (b,h,m) row of ET; wave-parallel scan + chunk prefetch.
// ---------------------------------------------------------------------------
__global__ __launch_bounds__(256) void cumsum_kernel(
    const bf16* __restrict__ ET, float* __restrict__ C)
{
    int row = blockIdx.x * 4 + (threadIdx.x >> 6);   // 1024 rows
    int lane = threadIdx.x & 63;
    int b = row >> 8, hm = row & 255;
    const bf16* src = ET + (size_t)row * 2048;
    float run = 0.f;
    float v = b2f(src[lane]);
    for (int ch = 0; ch < 32; ch++) {
        float vn = (ch < 31) ? b2f(src[(ch + 1) * 64 + lane]) : 0.f;
#pragma unroll
        for (int off = 1; off < 64; off <<= 1) {
            float o = __shfl_up(v, off, 64);
            if (lane >= off) v += o;
        }
        C[(size_t)(b * 2048 + ch * 64 + lane) * 256 + hm] = run + v;
        run += __shfl(v, 63, 64);
        v = vn;
    }
}

// ---------------------------------------------------------------------------
// attn1: one t-tile per block (longest first), double-buffered Kl/Sl,
// ONE barrier/iter; parallel softmax epilogue. grid (bh=16, tile=32).
// ---------------------------------------------------------------------------
__global__ __launch_bounds__(256) void attn1_mfma(
    const bf16* __restrict__ Q, const bf16* __restrict__ K,
    const bf16* __restrict__ ET, const float* __restrict__ C,
    bf16* __restrict__ U)
{
    __shared__ bf16 Kl[2][64 * 136];
    __shared__ bf16 Sl[2][64 * 72];
    __shared__ float okT[64 * 65];
    __shared__ float redm[256];
    __shared__ float reds[256];
    const int tid = threadIdx.x;
    const int w = tid >> 6, lane = tid & 63;
    const int l16 = lane & 15, q = lane >> 4;
    const int b = blockIdx.x >> 2, h = blockIdx.x & 3;
    const int t0 = (31 - (int)blockIdx.y) * 64;
    const int nIter = t0 / 64 + 1;
    f4v z = {0.f, 0.f, 0.f, 0.f};
    const int krow[4] = {tid >> 4, (256 + tid) >> 4, (512 + tid) >> 4, (768 + tid) >> 4};
    const int kcol = (tid & 15) * 8;
    const bf16* kbase = K + (size_t)b * Tn * KDn + h * HKn;
    const bf16* etrow = ET + (size_t)((b * 4 + h) * 64 + w * 16 + l16) * 2048;

    const bf16* qrow = Q + (size_t)(b * Tn + t0 + w * 16 + l16) * KDn + h * HKn;
    s8v qa[4];
#pragma unroll
    for (int kc = 0; kc < 4; kc++) qa[kc] = *(const s8v*)(qrow + kc * 32 + q * 8);
    f4v ok[4];
#pragma unroll
    for (int i = 0; i < 4; i++) ok[i] = z;
    s8v kreg[4];
#pragma unroll
    for (int c = 0; c < 4; c++)
        kreg[c] = *(const s8v*)(kbase + (size_t)krow[c] * KDn + kcol);
#pragma unroll
    for (int c = 0; c < 4; c++)
        *(s8v*)&Kl[0][krow[c] * 136 + kcol] = kreg[c];
    if (nIter > 1)
#pragma unroll
        for (int c = 0; c < 4; c++)
            kreg[c] = *(const s8v*)(kbase + (size_t)(64 + krow[c]) * KDn + kcol);
    __syncthreads();              // Kl[0] ready
    for (int i = 0; i < nIter; i++) {
        const int tau0 = i * 64;
        const int cur = i & 1, nxt = cur ^ 1;
        s8v ea[2];
#pragma unroll
        for (int kc = 0; kc < 2; kc++)
            ea[kc] = *(const s8v*)(etrow + tau0 + kc * 32 + q * 8);
        f4v sT[4];
#pragma unroll
        for (int fi = 0; fi < 4; fi++) sT[fi] = z;
#pragma unroll
        for (int kc = 0; kc < 4; kc++)
#pragma unroll
            for (int fi = 0; fi < 4; fi++) {
                s8v kb = *(s8v*)&Kl[cur][(fi * 16 + l16) * 136 + kc * 32 + q * 8];
                sT[fi] = mfma16(kb, qa[kc], sT[fi]);
            }
        const int tl = w * 16 + l16;
#pragma unroll
        for (int fi = 0; fi < 4; fi++) {
            alignas(8) bf16 pk[4];
#pragma unroll
            for (int r = 0; r < 4; r++) {
                int taul = fi * 16 + q * 4 + r;
                float v = sT[fi][r] * 0.08838834764831845f;
                pk[r] = ((tau0 + taul) <= (t0 + tl)) ? f2b(v) : f2b(0.f);
            }
            *(s4v*)&Sl[cur][tl * 72 + fi * 16 + q * 4] = *(s4v*)pk;
        }
        if (i + 1 < nIter) {
#pragma unroll
            for (int c = 0; c < 4; c++)
                *(s8v*)&Kl[nxt][krow[c] * 136 + kcol] = kreg[c];
            if (i + 2 < nIter)
#pragma unroll
                for (int c = 0; c < 4; c++)
                    kreg[c] = *(const s8v*)(kbase + (size_t)((i + 2) * 64 + krow[c]) * KDn + kcol);
        }
        __syncthreads();          // Sl[cur] + Kl[nxt] ready
#pragma unroll
        for (int kc = 0; kc < 2; kc++)
#pragma unroll
            for (int tf = 0; tf < 4; tf++) {
                s8v sb = *(s8v*)&Sl[cur][(tf * 16 + l16) * 72 + kc * 32 + q * 8];
                ok[tf] = mfma16(ea[kc], sb, ok[tf]);
            }
    }
#pragma unroll
    for (int tf = 0; tf < 4; tf++)
#pragma unroll
        for (int r = 0; r < 4; r++)
            okT[(w * 16 + q * 4 + r) * 65 + tf * 16 + l16] = ok[tf][r];
    __syncthreads();
    // parallel softmax: thread (t = tid&63, quarter qr = tid>>6) handles 16 m
    {
        const int t = tid & 63, qr = tid >> 6;
        size_t base = (size_t)(b * Tn + t0 + t) * 256 + h * 64;
        float vals[16];
        float mx = -1e30f;
#pragma unroll
        for (int j = 0; j < 16; j++) {
            int m = qr * 16 + j;
            float v = okT[m * 65 + t] / C[base + m];
            vals[j] = v;
            mx = fmaxf(mx, v);
        }
        redm[qr * 64 + t] = mx;
        __syncthreads();
        float MX = fmaxf(fmaxf(redm[t], redm[64 + t]), fmaxf(redm[128 + t], redm[192 + t]));
        float s = 0.f;
#pragma unroll
        for (int j = 0; j < 16; j++) {
            vals[j] = expf(vals[j] - MX);
            s += vals[j];
        }
        reds[qr * 64 + t] = s;
        __syncthreads();
        float inv = 1.f / (reds[t] + reds[64 + t] + reds[128 + t] + reds[192 + t]);
        alignas(16) bf16 tmp[16];
#pragma unroll
        for (int j = 0; j < 16; j++)
            tmp[j] = f2b(vals[j] * inv / C[base + qr * 16 + j]);
        *(s8v*)&U[base + qr * 16] = *(s8v*)&tmp[0];
        *(s8v*)&U[base + qr * 16 + 8] = *(s8v*)&tmp[8];
    }
}

// ---------------------------------------------------------------------------
// attn2: one t-tile per block (longest first), double-buffered El/Pl,
// ONE barrier/iter; fused RMSNorm*gn*silu(G) epilogue with per-zc Ot.
// grid (bh=16, tile=32).
// ---------------------------------------------------------------------------
__global__ __launch_bounds__(256) void attn2_mfma(
    const bf16* __restrict__ U, const bf16* __restrict__ E,
    const bf16* __restrict__ VT, const bf16* __restrict__ G,
    const bf16* __restrict__ gn, bf16* __restrict__ OV)
{
    __shared__ bf16 El[2][64 * 72];
    __shared__ bf16 Pl[2][64 * 72];
    __shared__ float Ot[64 * 68];
    __shared__ float swave[4][64];
    __shared__ float ssum[64];
    const int tid = threadIdx.x;
    const int w = tid >> 6, lane = tid & 63;
    const int l16 = lane & 15, q = lane >> 4;
    const int b = blockIdx.x >> 2, h = blockIdx.x & 3;
    const int t0 = (31 - (int)blockIdx.y) * 64;
    const int nIter = t0 / 64 + 1;
    f4v z = {0.f, 0.f, 0.f, 0.f};
    const int erow[2] = {tid >> 3, (256 + tid) >> 3};
    const int ecol = (tid & 7) * 8;
    const bf16* ebase = E + (size_t)b * Tn * 256 + h * 64;
    const bf16* vtbase = VT + (size_t)(b * 1024 + h * 256 + w * 16 + l16) * 2048;

    const bf16* urow = U + (size_t)(b * Tn + t0 + w * 16 + l16) * 256 + h * 64;
    s8v ua[2];
#pragma unroll
    for (int kc = 0; kc < 2; kc++) ua[kc] = *(const s8v*)(urow + kc * 32 + q * 8);
    f4v oacc[4][4];
#pragma unroll
    for (int zc = 0; zc < 4; zc++)
#pragma unroll
        for (int i = 0; i < 4; i++) oacc[zc][i] = z;
    s8v ereg[2];
#pragma unroll
    for (int c = 0; c < 2; c++)
        ereg[c] = *(const s8v*)(ebase + (size_t)erow[c] * 256 + ecol);
#pragma unroll
    for (int c = 0; c < 2; c++)
        *(s8v*)&El[0][erow[c] * 72 + ecol] = ereg[c];
    if (nIter > 1)
#pragma unroll
        for (int c = 0; c < 2; c++)
            ereg[c] = *(const s8v*)(ebase + (size_t)(64 + erow[c]) * 256 + ecol);
    __syncthreads();              // El[0] ready
    for (int i = 0; i < nIter; i++) {
        const int tau0 = i * 64;
        const int cur = i & 1, nxt = cur ^ 1;
        s8v vt[4][2];
#pragma unroll
        for (int zc = 0; zc < 4; zc++)
#pragma unroll
            for (int kc = 0; kc < 2; kc++)
                vt[zc][kc] = *(const s8v*)(vtbase + (size_t)(zc * 64) * 2048
                                           + tau0 + kc * 32 + q * 8);
        f4v pT[4];
#pragma unroll
        for (int fi = 0; fi < 4; fi++) pT[fi] = z;
#pragma unroll
        for (int kc = 0; kc < 2; kc++)
#pragma unroll
            for (int fi = 0; fi < 4; fi++) {
                s8v eb = *(s8v*)&El[cur][(fi * 16 + l16) * 72 + kc * 32 + q * 8];
                pT[fi] = mfma16(eb, ua[kc], pT[fi]);
            }
        const int tl = w * 16 + l16;
#pragma unroll
        for (int fi = 0; fi < 4; fi++) {
            alignas(8) bf16 pk[4];
#pragma unroll
            for (int r = 0; r < 4; r++) {
                int taul = fi * 16 + q * 4 + r;
                pk[r] = ((tau0 + taul) <= (t0 + tl)) ? f2b(pT[fi][r]) : f2b(0.f);
            }
            *(s4v*)&Pl[cur][tl * 72 + fi * 16 + q * 4] = *(s4v*)pk;
        }
        if (i + 1 < nIter) {
#pragma unroll
            for (int c = 0; c < 2; c++)
                *(s8v*)&El[nxt][erow[c] * 72 + ecol] = ereg[c];
            if (i + 2 < nIter)
#pragma unroll
                for (int c = 0; c < 2; c++)
                    ereg[c] = *(const s8v*)(ebase + (size_t)((i + 2) * 64 + erow[c]) * 256 + ecol);
        }
        __syncthreads();          // Pl[cur] + El[nxt] ready
        s8v pb[2][4];
#pragma unroll
        for (int kc = 0; kc < 2; kc++)
#pragma unroll
            for (int tf = 0; tf < 4; tf++)
                pb[kc][tf] = *(s8v*)&Pl[cur][(tf * 16 + l16) * 72 + kc * 32 + q * 8];
#pragma unroll
        for (int zc = 0; zc < 4; zc++)
#pragma unroll
            for (int kc = 0; kc < 2; kc++)
#pragma unroll
                for (int tf = 0; tf < 4; tf++)
                    oacc[zc][tf] = mfma16(vt[zc][kc], pb[kc][tf], oacc[zc][tf]);
    }
    // ---- epilogue: shuffle-reduced sum of squares + per-zc fused norm ----
    float part[4] = {0.f, 0.f, 0.f, 0.f};
#pragma unroll
    for (int zc = 0; zc < 4; zc++)
#pragma unroll
        for (int tf = 0; tf < 4; tf++)
#pragma unroll
            for (int r = 0; r < 4; r++)
                part[tf] += oacc[zc][tf][r] * oacc[zc][tf][r];
#pragma unroll
    for (int tf = 0; tf < 4; tf++) {
        part[tf] += __shfl_xor(part[tf], 16, 64);
        part[tf] += __shfl_xor(part[tf], 32, 64);
    }
    if (q == 0) {
#pragma unroll
        for (int tf = 0; tf < 4; tf++) swave[w][tf * 16 + l16] = part[tf];
    }
    const int trow = tid >> 2, vseg = (tid & 3) * 16;
    for (int zc = 0; zc < 4; zc++) {
        // deposit O^T for this zc: Ot[t][v0..63], pitch 68
#pragma unroll
        for (int tf = 0; tf < 4; tf++)
            *(f4v*)&Ot[(tf * 16 + l16) * 68 + w * 16 + q * 4] = oacc[zc][tf];
        __syncthreads();          // Ot (+ swave on first pass) ready
        if (zc == 0) {
            if (tid < 64)
                ssum[tid] = rsqrtf((swave[0][tid] + swave[1][tid] + swave[2][tid] + swave[3][tid])
                                   * (1.0f / 256.0f) + 1e-5f);
            __syncthreads();      // ssum ready
        }
        float rs = ssum[trow];
        size_t orow = (size_t)(b * Tn + t0 + trow) * VDn + h * HVn + zc * 64 + vseg;
        alignas(16) bf16 gh[16];
        *(s8v*)&gh[0] = *(const s8v*)&G[orow];
        *(s8v*)&gh[8] = *(const s8v*)&G[orow + 8];
        alignas(16) bf16 tmp[16];
#pragma unroll
        for (int i = 0; i < 16; i++) {
            float g = b2f(gh[i]);
            float sg = g / (1.f + expf(-g));
            float val = Ot[trow * 68 + vseg + i] * rs * b2f(gn[zc * 64 + vseg + i]) * sg;
            tmp[i] = f2b(val);
        }
        *(s8v*)&OV[orow] = *(s8v*)&tmp[0];
        *(s8v*)&OV[orow + 8] = *(s8v*)&tmp[8];
        __syncthreads();          // Ot consumed before next zc overwrites
    }
}

// ---------------------------------------------------------------------------
extern "C" void kernel_launch(void* const* d_in, const int* in_sizes, int n_in,
                              void* d_out, int out_size, void* d_ws, size_t ws_size,
                              hipStream_t stream)
{
    constexpr size_t MB = 1u << 20;
    char* w = (char*)d_ws;
    bf16* Xb   = (bf16*)(w + 0);                 // [0,16)  ; later OV
    bf16* OVb  = (bf16*)(w + 0);
    bf16* WoT  = (bf16*)(w + 16 * MB);           // [16,18)
    bf16* WgT  = (bf16*)(w + 18 * MB);           // [18,20)
    bf16* WqT  = (bf16*)(w + 20 * MB);           // [20,21)  (WkT contiguous after)
    bf16* WkT  = (bf16*)(w + 21 * MB);           // [21,22)
    bf16* WvT  = (bf16*)(w + 22 * MB);           // [22,24)
    bf16* WsT  = (bf16*)(w + 24 * MB);           // [24,24.5)
    bf16* gnwb = (bf16*)(w + 24 * MB + 524288);  // smalls in [24.5,25)
    bf16* qwb  = (bf16*)(w + 24 * MB + 532480);
    bf16* kwb  = (bf16*)(w + 24 * MB + 540672);
    bf16* vwb  = (bf16*)(w + 24 * MB + 548864);
    int*  flagp= (int*) (w + 24 * MB + 565248);
    bf16* Qb   = (bf16*)(w + 25 * MB);           // [25,33) ; later ghat [25,41)
    bf16* Kb   = (bf16*)(w + 33 * MB);           // [33,41)
    bf16* ghat = (bf16*)(w + 25 * MB);
    bf16* qkpre= (bf16*)(w + 41 * MB);           // [41,57) ; later E/ET/C
    bf16* vpre = (bf16*)(w + 41 * MB);
    bf16* Ebuf = (bf16*)(w + 41 * MB);           // [41,45)
    bf16* ETb  = (bf16*)(w + 45 * MB);           // [45,49)
    float* Cbuf= (float*)(w + 49 * MB);          // [49,57)
    bf16* Ubuf = (bf16*)(w + 57 * MB);           // [57,61)
    bf16* VT   = (bf16*)d_out;                   // V^T staged in d_out

    dim3 blk(256);
    probe_dtype_kernel<<<1, blk, 0, stream>>>(d_in[0], flagp);
    convert_kernel<<<16384, blk, 0, stream>>>(d_in[0], Xb, flagp, BT * Dn);
    convert_small_kernel<<<1, blk, 0, stream>>>(d_in[7], d_in[8], d_in[9], d_in[10],
                                                qwb, kwb, vwb, gnwb, flagp);
    convert_t6_kernel<<<1088, blk, 0, stream>>>(d_in[1], d_in[2], d_in[3], d_in[4],
                                                d_in[5], d_in[6],
                                                WqT, WkT, WvT, WsT, WgT, WoT, flagp);
    // merged q|k projection (N=1024: cols 0..511 q, 512..1023 k)
    gemm_mfma<0><<<dim3(8, 64), blk, 0, stream>>>(Xb, WqT, qkpre, nullptr, flagp, BT, 1024, Dn);
    conv_qk_rope_kernel<<<16384, blk, 0, stream>>>(qkpre, qwb, kwb, Qb, Kb);
    // v projection + transpose conv (vpre overwrites dead qkpre)
    gemm_mfma<0><<<dim3(8, 64), blk, 0, stream>>>(Xb, WvT, vpre, nullptr, flagp, BT, VDn, Dn);
    conv_v_t_kernel<<<dim3(16, 32, 4), blk, 0, stream>>>(vpre, vwb, VT);
    // slot gates: E (and ET) = exp(clip(X@Ws)); C = cumsum(ET)
    gemm_mfma<2><<<dim3(2, 64), blk, 0, stream>>>(Xb, WsT, Ebuf, ETb, flagp, BT, 256, Dn);
    cumsum_kernel<<<256, blk, 0, stream>>>(ETb, Cbuf);
    // attn1 -> U (1 tile/block, longest first, 1 barrier/iter)
    attn1_mfma<<<dim3(16, 32), blk, 0, stream>>>(Qb, Kb, ETb, Cbuf, Ubuf);
    // gate projection into dead Qb/Kb region
    gemm_mfma<0><<<dim3(8, 64), blk, 0, stream>>>(Xb, WgT, ghat, nullptr, flagp, BT, VDn, Dn);
    // attn2 with fused norm/gate -> OV (over dead Xb)
    attn2_mfma<<<dim3(16, 32), blk, 0, stream>>>(Ubuf, Ebuf, VT, ghat, gnwb, OVb);
    // output projection
    gemm_mfma<3><<<dim3(8, 64), blk, 0, stream>>>(OVb, WoT, d_out, nullptr, flagp, BT, Dn, VDn);
}

// Round 9
// 445.913 us; speedup vs baseline: 1.0554x; 1.0139x over previous
//
#include <hip/hip_runtime.h>
#include <hip/hip_bf16.h>
#include <math.h>

typedef __hip_bfloat16 bf16;
typedef short s8v __attribute__((ext_vector_type(8)));
typedef short s4v __attribute__((ext_vector_type(4)));
typedef float f4v __attribute__((ext_vector_type(4)));

__device__ __forceinline__ float b2f(bf16 x) { return __bfloat162float(x); }
__device__ __forceinline__ bf16 f2b(float x) { return __float2bfloat16(x); }
__device__ __forceinline__ f4v mfma16(s8v a, s8v b, f4v c) {
    return __builtin_amdgcn_mfma_f32_16x16x32_bf16(a, b, c, 0, 0, 0);
}
__device__ __forceinline__ void async16(const bf16* g, bf16* l) {
    __builtin_amdgcn_global_load_lds(
        (const __attribute__((address_space(1))) void*)g,
        (__attribute__((address_space(3))) void*)l, 16, 0, 0);
}

constexpr int Bn = 4, Tn = 2048, Dn = 1024, KDn = 512, VDn = 1024;
constexpr int Hn = 4, Mn = 64, HKn = 128, HVn = 256;
constexpr int BT = Bn * Tn;

// ---------------------------------------------------------------------------
__global__ __launch_bounds__(256) void probe_dtype_kernel(
    const void* __restrict__ x, int* __restrict__ flag)
{
    const bf16* xb = (const bf16*)x;
    float mx = 0.f;
    for (int i = threadIdx.x; i < 4096; i += 256) {
        float v = fabsf(b2f(xb[i]));
        if (isnan(v)) v = 1e30f;
        mx = fmaxf(mx, v);
    }
    __shared__ float red[256];
    red[threadIdx.x] = mx;
    __syncthreads();
    for (int s = 128; s > 0; s >>= 1) {
        if (threadIdx.x < s) red[threadIdx.x] = fmaxf(red[threadIdx.x], red[threadIdx.x + s]);
        __syncthreads();
    }
    if (threadIdx.x == 0) flag[0] = (red[0] > 1e6f) ? 1 : 0;
}

__global__ __launch_bounds__(256) void convert_kernel(
    const void* __restrict__ src, bf16* __restrict__ dst,
    const int* __restrict__ flag, int n)
{
    int is32 = flag[0];
    int i0 = (blockIdx.x * 256 + threadIdx.x) * 4;
#pragma unroll
    for (int j = 0; j < 4; j++) {
        int i = i0 + j;
        if (i < n)
            dst[i] = is32 ? f2b(((const float*)src)[i]) : ((const bf16*)src)[i];
    }
}

__global__ __launch_bounds__(256) void convert_small_kernel(
    const void* __restrict__ q, const void* __restrict__ k,
    const void* __restrict__ v, const void* __restrict__ g,
    bf16* __restrict__ qd, bf16* __restrict__ kd,
    bf16* __restrict__ vd, bf16* __restrict__ gd,
    const int* __restrict__ flag)
{
    int is32 = flag[0];
    for (int i = threadIdx.x; i < 8448; i += 256) {
        const void* s; bf16* d; int l;
        if (i < 2048)      { s = q; d = qd; l = i; }
        else if (i < 4096) { s = k; d = kd; l = i - 2048; }
        else if (i < 8192) { s = v; d = vd; l = i - 4096; }
        else               { s = g; d = gd; l = i - 8192; }
        d[l] = is32 ? f2b(((const float*)s)[l]) : ((const bf16*)s)[l];
    }
}

__global__ __launch_bounds__(256) void convert_t6_kernel(
    const void* s0, const void* s1, const void* s2, const void* s3,
    const void* s4, const void* s5,
    bf16* d0, bf16* d1, bf16* d2, bf16* d3, bf16* d4, bf16* d5,
    const int* __restrict__ flag)
{
    __shared__ bf16 tile[64 * 72];
    int is32 = flag[0];
    int nb = blockIdx.x;
    const void* src; bf16* dst; int K, N, loc;
    if (nb < 128)       { src = s0; dst = d0; K = 1024; N = 512;  loc = nb; }
    else if (nb < 256)  { src = s1; dst = d1; K = 1024; N = 512;  loc = nb - 128; }
    else if (nb < 512)  { src = s2; dst = d2; K = 1024; N = 1024; loc = nb - 256; }
    else if (nb < 576)  { src = s3; dst = d3; K = 1024; N = 256;  loc = nb - 512; }
    else if (nb < 832)  { src = s4; dst = d4; K = 1024; N = 1024; loc = nb - 576; }
    else                { src = s5; dst = d5; K = 1024; N = 1024; loc = nb - 832; }
    int nt = N >> 6;
    int n0 = (loc % nt) * 64, k0 = (loc / nt) * 64;
    int tid = threadIdx.x;
    int r = tid >> 2, seg = (tid & 3) * 16;
#pragma unroll
    for (int i = 0; i < 16; i++) {
        size_t gi = (size_t)(k0 + r) * N + n0 + seg + i;
        float v = is32 ? ((const float*)src)[gi] : b2f(((const bf16*)src)[gi]);
        tile[r * 72 + seg + i] = f2b(v);
    }
    __syncthreads();
    bf16 tmp[16];
#pragma unroll
    for (int i = 0; i < 16; i++) tmp[i] = tile[(seg + i) * 72 + r];
    size_t o = (size_t)(n0 + r) * K + k0 + seg;
    *(s8v*)&dst[o] = *(s8v*)&tmp[0];
    *(s8v*)&dst[o + 8] = *(s8v*)&tmp[8];
}

// ---------------------------------------------------------------------------
// MFMA GEMM (m97 recipe). EP: 0 bf16; 2 exp-clip -> transposed ET only;
// 3 dynamic fp32/bf16 per flag.
// ---------------------------------------------------------------------------
template <int EP>
__global__ __launch_bounds__(256) void gemm_mfma(
    const bf16* __restrict__ A, const bf16* __restrict__ BT,
    void* __restrict__ Cout, bf16* __restrict__ Cout2,
    const int* __restrict__ flag, int M, int N, int K)
{
    __shared__ bf16 Xs[128 * 64];
    __shared__ bf16 Ws2[128 * 64];
    const int tid = threadIdx.x;
    const int w = tid >> 6, lane = tid & 63;
    const int l16 = lane & 15, q = lane >> 4;
    const int wr = w >> 1, wc = w & 1;
    const int m0 = blockIdx.y * 128, n0 = blockIdx.x * 128;
    int dyn = 0;
    if (EP == 3) dyn = flag[0];

    const int srow = w * 32 + (lane >> 3);
    const int scol = (lane & 7) * 8;
    const bf16* ga = A + (size_t)(m0 + srow) * K + scol;
    const bf16* gb = BT + (size_t)(n0 + srow) * K + scol;

    f4v acc[4][4];
    f4v z = {0.f, 0.f, 0.f, 0.f};
#pragma unroll
    for (int i = 0; i < 4; i++)
#pragma unroll
        for (int j = 0; j < 4; j++) acc[i][j] = z;

    for (int k0 = 0; k0 < K; k0 += 64) {
#pragma unroll
        for (int c = 0; c < 4; c++) {
            async16(ga + (size_t)(c * 8) * K + k0, &Xs[(w * 32 + c * 8) * 64]);
            async16(gb + (size_t)(c * 8) * K + k0, &Ws2[(w * 32 + c * 8) * 64]);
        }
        __syncthreads();
#pragma unroll
        for (int kq = 0; kq < 2; kq++) {
            s8v a[4], b[4];
#pragma unroll
            for (int mi = 0; mi < 4; mi++)
                a[mi] = *(s8v*)&Xs[(wr * 64 + mi * 16 + l16) * 64 + kq * 32 + q * 8];
#pragma unroll
            for (int ni = 0; ni < 4; ni++)
                b[ni] = *(s8v*)&Ws2[(wc * 64 + ni * 16 + l16) * 64 + kq * 32 + q * 8];
#pragma unroll
            for (int mi = 0; mi < 4; mi++)
#pragma unroll
                for (int ni = 0; ni < 4; ni++)
                    acc[mi][ni] = mfma16(a[mi], b[ni], acc[mi][ni]);
        }
        __syncthreads();
    }
#pragma unroll
    for (int mi = 0; mi < 4; mi++)
#pragma unroll
        for (int ni = 0; ni < 4; ni++)
#pragma unroll
            for (int r = 0; r < 4; r++) {
                int row = m0 + wr * 64 + mi * 16 + q * 4 + r;
                int col = n0 + wc * 64 + ni * 16 + l16;
                size_t idx = (size_t)row * N + col;
                float v = acc[mi][ni][r];
                if (EP == 2) {
                    float cl = fminf(32.f, fmaxf(-32.f, v));
                    bf16 e = f2b(expf(cl));
                    int b_ = row >> 11, t_ = row & 2047;
                    int h_ = col >> 6, m_ = col & 63;
                    Cout2[((size_t)((b_ * 4 + h_) * 64 + m_)) * 2048 + t_] = e;
                } else if (EP == 3) {
                    if (dyn) ((float*)Cout)[idx] = v;
                    else ((bf16*)Cout)[idx] = f2b(v);
                } else {
                    ((bf16*)Cout)[idx] = f2b(v);
                }
            }
}

// ---------------------------------------------------------------------------
// conv+silu+rope for q only (pre row stride 1024, cols 0..511).
// ---------------------------------------------------------------------------
__global__ __launch_bounds__(256) void conv_q_kernel(
    const bf16* __restrict__ pre, const bf16* __restrict__ w,
    bf16* __restrict__ out)
{
    int gid = blockIdx.x * 256 + threadIdx.x;  // B*T*H*64
    int d = gid & 63;
    int h = (gid >> 6) & 3;
    int t = (gid >> 8) & 2047;
    int b = gid >> 19;
    int clo = h * HKn + d, chi = clo + 64;
    float ylo = 0.f, yhi = 0.f;
#pragma unroll
    for (int j = 0; j < 4; j++) {
        int tt = t - 3 + j;
        if (tt >= 0) {
            size_t rb = (size_t)(b * Tn + tt) * 1024;
            ylo += b2f(pre[rb + clo]) * b2f(w[clo * 4 + j]);
            yhi += b2f(pre[rb + chi]) * b2f(w[chi * 4 + j]);
        }
    }
    ylo = ylo / (1.f + expf(-ylo));
    yhi = yhi / (1.f + expf(-yhi));
    float invf = powf(10000.f, -(float)d * (1.f / 64.f));
    float th = (float)t * invf;
    float c = cosf(th), s = sinf(th);
    size_t rowbase = (size_t)(b * Tn + t) * KDn;
    out[rowbase + clo] = f2b(ylo * c - yhi * s);
    out[rowbase + chi] = f2b(yhi * c + ylo * s);
}

// ---------------------------------------------------------------------------
// conv+silu+rope for k, output TRANSPOSED: KT[(b*4+h)*128 + d][t].
// grid (b,h,ttile32). Threads: dp = tid>>2 (0..63 rope pair), tq = tid&3.
// ---------------------------------------------------------------------------
__global__ __launch_bounds__(256) void conv_k_t_kernel(
    const bf16* __restrict__ pre, const bf16* __restrict__ w,
    bf16* __restrict__ KT)
{
    __shared__ bf16 tile[128 * 72];
    const int b = blockIdx.z, h = blockIdx.y, tt = blockIdx.x;
    const int tid = threadIdx.x;
    const int dp = tid >> 2, tq = tid & 3;
    const int clo = 512 + h * 128 + dp, chi = clo + 64;
    const float w0l = b2f(w[(h * 128 + dp) * 4 + 0]), w1l = b2f(w[(h * 128 + dp) * 4 + 1]),
                w2l = b2f(w[(h * 128 + dp) * 4 + 2]), w3l = b2f(w[(h * 128 + dp) * 4 + 3]);
    const float w0h = b2f(w[(h * 128 + dp + 64) * 4 + 0]), w1h = b2f(w[(h * 128 + dp + 64) * 4 + 1]),
                w2h = b2f(w[(h * 128 + dp + 64) * 4 + 2]), w3h = b2f(w[(h * 128 + dp + 64) * 4 + 3]);
    const float invf = powf(10000.f, -(float)dp * (1.f / 64.f));
    // streaming window: history x[t-3],x[t-2],x[t-1]
    float l0 = 0.f, l1 = 0.f, l2 = 0.f, h0 = 0.f, h1 = 0.f, h2 = 0.f;
    int tg0 = tt * 64 + tq * 16;
#pragma unroll
    for (int p = 0; p < 3; p++) {
        int tg = tg0 - 3 + p;
        float xl = 0.f, xh = 0.f;
        if (tg >= 0) {
            size_t rb = (size_t)(b * Tn + tg) * 1024;
            xl = b2f(pre[rb + clo]);
            xh = b2f(pre[rb + chi]);
        }
        l0 = l1; l1 = l2; l2 = xl;
        h0 = h1; h1 = h2; h2 = xh;
    }
    for (int i = 0; i < 16; i++) {
        int tg = tg0 + i;
        size_t rb = (size_t)(b * Tn + tg) * 1024;
        float xl = b2f(pre[rb + clo]);
        float xh = b2f(pre[rb + chi]);
        float ylo = l0 * w0l + l1 * w1l + l2 * w2l + xl * w3l;
        float yhi = h0 * w0h + h1 * w1h + h2 * w2h + xh * w3h;
        l0 = l1; l1 = l2; l2 = xl;
        h0 = h1; h1 = h2; h2 = xh;
        ylo = ylo / (1.f + expf(-ylo));
        yhi = yhi / (1.f + expf(-yhi));
        float th = (float)tg * invf;
        float c = cosf(th), s = sinf(th);
        int tl = tq * 16 + i;
        tile[dp * 72 + tl] = f2b(ylo * c - yhi * s);
        tile[(dp + 64) * 72 + tl] = f2b(yhi * c + ylo * s);
    }
    __syncthreads();
#pragma unroll
    for (int c = 0; c < 4; c++) {
        int idx = c * 256 + tid;
        int ch = idx >> 3, t8 = (idx & 7) * 8;
        s8v v = *(s8v*)&tile[ch * 72 + t8];
        *(s8v*)&KT[((size_t)((b * 4 + h) * 128 + ch)) * 2048 + tt * 64 + t8] = v;
    }
}

// ---------------------------------------------------------------------------
// conv + silu for v -> VT[b*1024 + c][t] (unchanged).
// ---------------------------------------------------------------------------
__global__ __launch_bounds__(256) void conv_v_t_kernel(
    const bf16* __restrict__ pre, const bf16* __restrict__ w,
    bf16* __restrict__ VT)
{
    __shared__ bf16 tile[64 * 72];
    int c0 = blockIdx.x * 64, t0 = blockIdx.y * 64, b = blockIdx.z;
    int tid = threadIdx.x;
    int row = tid >> 2, seg = (tid & 3) * 16;
    float y[16];
#pragma unroll
    for (int i = 0; i < 16; i++) y[i] = 0.f;
#pragma unroll
    for (int j = 0; j < 4; j++) {
        int tt = t0 + row - 3 + j;
        if (tt >= 0) {
            const bf16* p = &pre[(size_t)(b * Tn + tt) * VDn + c0 + seg];
#pragma unroll
            for (int i = 0; i < 16; i++)
                y[i] += b2f(p[i]) * b2f(w[(c0 + seg + i) * 4 + j]);
        }
    }
#pragma unroll
    for (int i = 0; i < 16; i++) {
        float v = y[i] / (1.f + expf(-y[i]));
        tile[row * 72 + seg + i] = f2b(v);
    }
    __syncthreads();
    bf16 tmp[16];
#pragma unroll
    for (int i = 0; i < 16; i++) tmp[i] = tile[(seg + i) * 72 + row];
    size_t o = (size_t)(b * 1024 + c0 + row) * 2048 + t0 + seg;
    *(s8v*)&VT[o] = *(s8v*)&tmp[0];
    *(s8v*)&VT[o + 8] = *(s8v*)&tmp[8];
}

// ---------------------------------------------------------------------------
// cumsum checkpoints: Ccp[(b*32+j)*256 + hm] = sum of E over tiles < j.
// ---------------------------------------------------------------------------
__global__ __launch_bounds__(256) void cumsum_ccp_kernel(
    const bf16* __restrict__ ET, float* __restrict__ Ccp)
{
    int row = blockIdx.x * 4 + (threadIdx.x >> 6);   // 1024 rows = b*256 + hm
    int lane = threadIdx.x & 63;
    int b = row >> 8, hm = row & 255;
    const bf16* src = ET + (size_t)row * 2048;
    float run = 0.f;
    for (int ch = 0; ch < 32; ch++) {
        if (lane == 0) Ccp[(size_t)(b * 32 + ch) * 256 + hm] = run;
        float v = b2f(src[ch * 64 + lane]);
#pragma unroll
        for (int off = 1; off < 64; off <<= 1) {
            float o = __shfl_up(v, off, 64);
            if (lane >= off) v += o;
        }
        run += __shfl(v, 63, 64);
    }
}

// ---------------------------------------------------------------------------
// Prefix-state scan. blocks 0..63: Sv-scan (bh, vc): SvT_j[v][m] exclusive
// prefixes of E^T V. blocks 64..95: H-scan (bh, kc2): HT_j[m][k] prefixes of
// (K^T E)^T i.e. rows m, k contiguous. MFMA accumulators = running state.
// ---------------------------------------------------------------------------
__global__ __launch_bounds__(256) void scan_state_kernel(
    const bf16* __restrict__ ET, const bf16* __restrict__ KT,
    const bf16* __restrict__ VT,
    bf16* __restrict__ Svp, bf16* __restrict__ HpA, bf16* __restrict__ HpB)
{
    const int tid = threadIdx.x;
    const int w = tid >> 6, lane = tid & 63;
    const int l16 = lane & 15, q = lane >> 4;
    f4v z = {0.f, 0.f, 0.f, 0.f};
    if (blockIdx.x < 64) {
        const int bh = blockIdx.x >> 2, vc = blockIdx.x & 3;
        const int b = bh >> 2, h = bh & 3;
        const bf16* vtrow = VT + (size_t)(b * 1024 + h * 256 + vc * 64 + w * 16 + l16) * 2048;
        f4v acc[4];
#pragma unroll
        for (int i = 0; i < 4; i++) acc[i] = z;
        for (int j = 0; j < 32; j++) {
            // emit exclusive prefix: rows v = vc*64+w*16+q*4+r, col m = mf*16+l16
#pragma unroll
            for (int mf = 0; mf < 4; mf++)
#pragma unroll
                for (int r = 0; r < 4; r++)
                    Svp[((size_t)((bh * 32 + j) * 256 + vc * 64 + w * 16 + q * 4 + r)) * 64
                        + mf * 16 + l16] = f2b(acc[mf][r]);
#pragma unroll
            for (int kc = 0; kc < 2; kc++) {
                s8v va = *(const s8v*)(vtrow + j * 64 + kc * 32 + q * 8);
#pragma unroll
                for (int mf = 0; mf < 4; mf++) {
                    s8v eb = *(const s8v*)(ET + (size_t)(bh * 64 + mf * 16 + l16) * 2048
                                           + j * 64 + kc * 32 + q * 8);
                    acc[mf] = mfma16(va, eb, acc[mf]);
                }
            }
        }
    } else {
        const int idx = blockIdx.x - 64;
        const int bh = idx >> 1, kc2 = idx & 1;
        bf16* hp = (bh < 12) ? (HpA + (size_t)bh * 262144)
                             : (HpB + (size_t)(bh - 12) * 262144);
        const bf16* etrow = ET + (size_t)(bh * 64 + w * 16 + l16) * 2048;
        f4v acc[4];
#pragma unroll
        for (int i = 0; i < 4; i++) acc[i] = z;
        for (int j = 0; j < 32; j++) {
            // emit: rows m = w*16+q*4+r, col k = kc2*64 + kf*16+l16
#pragma unroll
            for (int kf = 0; kf < 4; kf++)
#pragma unroll
                for (int r = 0; r < 4; r++)
                    hp[((size_t)(j * 64 + w * 16 + q * 4 + r)) * 128
                       + kc2 * 64 + kf * 16 + l16] = f2b(acc[kf][r]);
#pragma unroll
            for (int kc = 0; kc < 2; kc++) {
                s8v ea = *(const s8v*)(etrow + j * 64 + kc * 32 + q * 8);
#pragma unroll
                for (int kf = 0; kf < 4; kf++) {
                    s8v kb = *(const s8v*)(KT + (size_t)(bh * 128 + kc2 * 64 + kf * 16 + l16) * 2048
                                           + j * 64 + kc * 32 + q * 8);
                    acc[kf] = mfma16(ea, kb, acc[kf]);
                }
            }
        }
    }
}

// ---------------------------------------------------------------------------
// Fused attention: per (bh, tile j): ok = Q*Hpre + masked local; softmax -> U
// (LDS only); O = U*Svpre + masked local PV; fused RMSNorm*gn*silu(gate).
// Fixed work per block, ~10 barriers, no loop over tau.
// ---------------------------------------------------------------------------
__global__ __launch_bounds__(256) void attn12_mfma(
    const bf16* __restrict__ Q, const bf16* __restrict__ KT,
    const bf16* __restrict__ ET, const float* __restrict__ Ccp,
    const bf16* __restrict__ HpA, const bf16* __restrict__ HpB,
    const bf16* __restrict__ Svp, const bf16* __restrict__ VT,
    const bf16* __restrict__ gate, const bf16* __restrict__ gn,
    bf16* __restrict__ OV)
{
    __shared__ char smem[53760];
    bf16*  Kloc = (bf16*)smem;                    // [64tau][136]   P0-P1
    float* Ot   = (float*)smem;                   // [64t][68]      P6
    bf16*  Sl   = (bf16*)(smem + 17408);          // [64t][72]      P1-P2
    bf16*  Ct   = (bf16*)(smem + 17408);          // [64m][72]      P3
    bf16*  Etl  = (bf16*)(smem + 17408);          // [64tau][72]    P4
    float* okT  = (float*)(smem + 26624);         // [64m][65]      P2-P3
    bf16*  Pl   = (bf16*)(smem + 26624);          // [64t][72]      P4-P5
    bf16*  Ul   = (bf16*)(smem + 43264);          // [64t][72]      P3-P5
    float* swave= (float*)(smem + 52480);         // [4][64]
    float* ssum = (float*)(smem + 53504);         // [64]
    const int tid = threadIdx.x;
    const int w = tid >> 6, lane = tid & 63;
    const int l16 = lane & 15, q = lane >> 4;
    const int bh = blockIdx.x, b = bh >> 2, h = bh & 3;
    const int j = blockIdx.y, j64 = j * 64;
    f4v z = {0.f, 0.f, 0.f, 0.f};
    const bf16* hp = (bh < 12) ? (HpA + (size_t)bh * 262144)
                               : (HpB + (size_t)(bh - 12) * 262144);

    // stage Kloc (KT tile j -> [tau][k])
#pragma unroll
    for (int c = 0; c < 4; c++) {
        int idx = c * 256 + tid;
        int kr = idx >> 3, t8 = (idx & 7) * 8;
        alignas(16) bf16 tmp[8];
        *(s8v*)tmp = *(const s8v*)&KT[((size_t)(bh * 128 + kr)) * 2048 + j64 + t8];
#pragma unroll
        for (int i = 0; i < 8; i++) Kloc[(t8 + i) * 136 + kr] = tmp[i];
    }
    const bf16* qrow = Q + (size_t)(b * 2048 + j64 + w * 16 + l16) * 512 + h * 128;
    s8v qa[4];
#pragma unroll
    for (int kc = 0; kc < 4; kc++) qa[kc] = *(const s8v*)(qrow + kc * 32 + q * 8);
    __syncthreads();                               // Kloc ready
    // P1: ST[tau][t(w-block)] = Kloc x Q
    {
        f4v sT[4];
#pragma unroll
        for (int fi = 0; fi < 4; fi++) sT[fi] = z;
#pragma unroll
        for (int kc = 0; kc < 4; kc++)
#pragma unroll
            for (int fi = 0; fi < 4; fi++) {
                s8v kb = *(s8v*)&Kloc[(fi * 16 + l16) * 136 + kc * 32 + q * 8];
                sT[fi] = mfma16(kb, qa[kc], sT[fi]);
            }
        const int tl = w * 16 + l16;
#pragma unroll
        for (int fi = 0; fi < 4; fi++) {
            alignas(8) bf16 pk[4];
#pragma unroll
            for (int r = 0; r < 4; r++) {
                int taul = fi * 16 + q * 4 + r;
                pk[r] = (taul <= tl) ? f2b(sT[fi][r]) : f2b(0.f);
            }
            *(s4v*)&Sl[tl * 72 + fi * 16 + q * 4] = *(s4v*)pk;
        }
    }
    __syncthreads();                               // Sl ready, Kloc dead
    // P2: okT[m(w-block)][t] = ET_local x Sl + Hpre x Q
    {
        f4v ok[4];
#pragma unroll
        for (int i = 0; i < 4; i++) ok[i] = z;
        const bf16* etrow = ET + (size_t)(bh * 64 + w * 16 + l16) * 2048 + j64;
#pragma unroll
        for (int kc = 0; kc < 2; kc++) {
            s8v ea = *(const s8v*)(etrow + kc * 32 + q * 8);
#pragma unroll
            for (int tf = 0; tf < 4; tf++) {
                s8v sb = *(s8v*)&Sl[(tf * 16 + l16) * 72 + kc * 32 + q * 8];
                ok[tf] = mfma16(ea, sb, ok[tf]);
            }
        }
        const bf16* hrow = hp + (size_t)(j64 + w * 16 + l16) * 128;
#pragma unroll
        for (int kc = 0; kc < 4; kc++) {
            s8v ha = *(const s8v*)(hrow + kc * 32 + q * 8);
#pragma unroll
            for (int tf = 0; tf < 4; tf++) {
                s8v qb = *(const s8v*)(Q + (size_t)(b * 2048 + j64 + tf * 16 + l16) * 512
                                       + h * 128 + kc * 32 + q * 8);
                ok[tf] = mfma16(ha, qb, ok[tf]);
            }
        }
#pragma unroll
        for (int tf = 0; tf < 4; tf++)
#pragma unroll
            for (int r = 0; r < 4; r++)
                okT[(w * 16 + q * 4 + r) * 65 + tf * 16 + l16] = ok[tf][r];
    }
    __syncthreads();                               // okT ready, Sl dead
    // P3a: Ct[m][tau] = Ccp + inclusive prefix of ET tile (bf16)
    for (int mi = 0; mi < 16; mi++) {
        int m = w * 16 + mi;
        float v = b2f(ET[(size_t)(bh * 64 + m) * 2048 + j64 + lane]);
#pragma unroll
        for (int off = 1; off < 64; off <<= 1) {
            float o = __shfl_up(v, off, 64);
            if (lane >= off) v += o;
        }
        float c0 = Ccp[(size_t)(b * 32 + j) * 256 + h * 64 + m];
        Ct[m * 72 + lane] = f2b(c0 + v);
    }
    __syncthreads();                               // Ct ready
    // P3b: softmax rows t -> Ul
    if (tid < 64) {
        const int t = tid;
        const float scale = 0.08838834764831845f;
        float mx = -1e30f;
        for (int m = 0; m < 64; m++) {
            float c = b2f(Ct[m * 72 + t]);
            float v = okT[m * 65 + t] * scale / c;
            okT[m * 65 + t] = v;
            mx = fmaxf(mx, v);
        }
        float sum = 0.f;
        for (int m = 0; m < 64; m++) {
            float e = expf(okT[m * 65 + t] - mx);
            okT[m * 65 + t] = e;
            sum += e;
        }
        float inv = 1.f / sum;
        for (int m = 0; m < 64; m++) {
            float c = b2f(Ct[m * 72 + t]);
            Ul[t * 72 + m] = f2b(okT[m * 65 + t] * inv / c);
        }
    }
    __syncthreads();                               // Ul ready; okT,Ct dead
    // P4a: stage Etl [tau][m]
#pragma unroll
    for (int c = 0; c < 2; c++) {
        int idx = c * 256 + tid;
        int mr = idx >> 3, t8 = (idx & 7) * 8;
        alignas(16) bf16 tmp[8];
        *(s8v*)tmp = *(const s8v*)&ET[(size_t)(bh * 64 + mr) * 2048 + j64 + t8];
#pragma unroll
        for (int i = 0; i < 8; i++) Etl[(t8 + i) * 72 + mr] = tmp[i];
    }
    __syncthreads();                               // Etl ready
    // P4b: PT[tau][t(w-block)] = Etl x Ul, masked -> Pl
    {
        s8v ub[2];
#pragma unroll
        for (int kc = 0; kc < 2; kc++)
            ub[kc] = *(s8v*)&Ul[(w * 16 + l16) * 72 + kc * 32 + q * 8];
        f4v pT[4];
#pragma unroll
        for (int fi = 0; fi < 4; fi++) pT[fi] = z;
#pragma unroll
        for (int kc = 0; kc < 2; kc++)
#pragma unroll
            for (int fi = 0; fi < 4; fi++) {
                s8v eb = *(s8v*)&Etl[(fi * 16 + l16) * 72 + kc * 32 + q * 8];
                pT[fi] = mfma16(eb, ub[kc], pT[fi]);
            }
        const int tl = w * 16 + l16;
#pragma unroll
        for (int fi = 0; fi < 4; fi++) {
            alignas(8) bf16 pk[4];
#pragma unroll
            for (int r = 0; r < 4; r++) {
                int taul = fi * 16 + q * 4 + r;
                pk[r] = (taul <= tl) ? f2b(pT[fi][r]) : f2b(0.f);
            }
            *(s4v*)&Pl[tl * 72 + fi * 16 + q * 4] = *(s4v*)pk;
        }
    }
    __syncthreads();                               // Pl ready
    // P5: OT[v][t] = VT x Pl + Svp x Ul
    f4v oacc[4][4];
#pragma unroll
    for (int zc = 0; zc < 4; zc++)
#pragma unroll
        for (int i = 0; i < 4; i++) oacc[zc][i] = z;
    {
        const bf16* vtrow = VT + (size_t)(b * 1024 + h * 256 + w * 16 + l16) * 2048 + j64;
        const bf16* svrow = Svp + (size_t)((bh * 32 + j) * 256 + w * 16 + l16) * 64;
#pragma unroll
        for (int kc = 0; kc < 2; kc++) {
            s8v pb[4], ub2[4];
#pragma unroll
            for (int tf = 0; tf < 4; tf++) {
                pb[tf] = *(s8v*)&Pl[(tf * 16 + l16) * 72 + kc * 32 + q * 8];
                ub2[tf] = *(s8v*)&Ul[(tf * 16 + l16) * 72 + kc * 32 + q * 8];
            }
#pragma unroll
            for (int zc = 0; zc < 4; zc++) {
                s8v vt = *(const s8v*)(vtrow + (size_t)(zc * 64) * 2048 + kc * 32 + q * 8);
                s8v sv = *(const s8v*)(svrow + (size_t)(zc * 64) * 64 + kc * 32 + q * 8);
#pragma unroll
                for (int tf = 0; tf < 4; tf++) {
                    oacc[zc][tf] = mfma16(vt, pb[tf], oacc[zc][tf]);
                    oacc[zc][tf] = mfma16(sv, ub2[tf], oacc[zc][tf]);
                }
            }
        }
    }
    // P6: fused RMSNorm * gn * silu(gate) epilogue
    float part[4] = {0.f, 0.f, 0.f, 0.f};
#pragma unroll
    for (int zc = 0; zc < 4; zc++)
#pragma unroll
        for (int tf = 0; tf < 4; tf++)
#pragma unroll
            for (int r = 0; r < 4; r++)
                part[tf] += oacc[zc][tf][r] * oacc[zc][tf][r];
#pragma unroll
    for (int tf = 0; tf < 4; tf++) {
        part[tf] += __shfl_xor(part[tf], 16, 64);
        part[tf] += __shfl_xor(part[tf], 32, 64);
    }
    if (q == 0) {
#pragma unroll
        for (int tf = 0; tf < 4; tf++) swave[w * 64 + tf * 16 + l16] = part[tf];
    }
    const int trow = tid >> 2, vseg = (tid & 3) * 16;
    for (int zc = 0; zc < 4; zc++) {
#pragma unroll
        for (int tf = 0; tf < 4; tf++)
            *(f4v*)&Ot[(tf * 16 + l16) * 68 + w * 16 + q * 4] = oacc[zc][tf];
        __syncthreads();                           // Ot (+swave first pass)
        if (zc == 0) {
            if (tid < 64)
                ssum[tid] = rsqrtf((swave[tid] + swave[64 + tid] + swave[128 + tid]
                                    + swave[192 + tid]) * (1.0f / 256.0f) + 1e-5f);
            __syncthreads();
        }
        float rs = ssum[trow];
        size_t orow = (size_t)(b * 2048 + j64 + trow) * 1024 + h * 256 + zc * 64 + vseg;
        alignas(16) bf16 gh[16];
        *(s8v*)&gh[0] = *(const s8v*)&gate[orow];
        *(s8v*)&gh[8] = *(const s8v*)&gate[orow + 8];
        alignas(16) bf16 tmp[16];
#pragma unroll
        for (int i = 0; i < 16; i++) {
            float g = b2f(gh[i]);
            float sg = g / (1.f + expf(-g));
            float val = Ot[trow * 68 + vseg + i] * rs * b2f(gn[zc * 64 + vseg + i]) * sg;
            tmp[i] = f2b(val);
        }
        *(s8v*)&OV[orow] = *(s8v*)&tmp[0];
        *(s8v*)&OV[orow + 8] = *(s8v*)&tmp[8];
        __syncthreads();                           // Ot consumed
    }
}

// ---------------------------------------------------------------------------
extern "C" void kernel_launch(void* const* d_in, const int* in_sizes, int n_in,
                              void* d_out, int out_size, void* d_ws, size_t ws_size,
                              hipStream_t stream)
{
    constexpr size_t MB = 1u << 20;
    char* w = (char*)d_ws;
    bf16* Xb   = (bf16*)(w + 0);                 // [0,16) -> OV after GEMM_g
    bf16* OVb  = (bf16*)(w + 0);
    bf16* WoT  = (bf16*)(w + 16 * MB);           // [16,18)
    bf16* WqkT = (bf16*)(w + 18 * MB);           // [18,20): WqT+WkT contiguous
    bf16* WkT  = (bf16*)(w + 19 * MB);
    bf16* WgT  = (bf16*)(w + 20 * MB);           // [20,22)
    bf16* WvT  = (bf16*)(w + 22 * MB);           // [22,24)
    bf16* WsT  = (bf16*)(w + 24 * MB);           // [24,24.5)
    bf16* HpA  = (bf16*)(w + 18 * MB);           // [18,24) after GEMMs (12 bh)
    bf16* gnwb = (bf16*)(w + 24 * MB + 524288);  // smalls [24.5,25) permanent
    bf16* qwb  = (bf16*)(w + 24 * MB + 532480);
    bf16* kwb  = (bf16*)(w + 24 * MB + 540672);
    bf16* vwb  = (bf16*)(w + 24 * MB + 548864);
    int*  flagp= (int*) (w + 24 * MB + 565248);
    bf16* pre  = (bf16*)(w + 25 * MB);           // [25,41) -> Svp after convs
    bf16* Svp  = (bf16*)(w + 25 * MB);
    bf16* ETb  = (bf16*)(w + 41 * MB);           // [41,45)
    bf16* Qb   = (bf16*)(w + 45 * MB);           // [45,53)
    bf16* KTb  = (bf16*)(w + 53 * MB);           // [53,61)
    float* Ccp = (float*)(w + 61 * MB);          // [61,61.25)
    bf16* HpB  = (bf16*)(w + 61 * MB + 262144);  // [61.25,63.25) (4 bh)
    bf16* VT   = (bf16*)d_out;                   // d_out[0,16MB)
    bf16* gate = (bf16*)d_out + 8 * 1024 * 1024; // d_out[16,32MB)

    dim3 blk(256);
    probe_dtype_kernel<<<1, blk, 0, stream>>>(d_in[0], flagp);
    convert_kernel<<<16384, blk, 0, stream>>>(d_in[0], Xb, flagp, BT * Dn);
    convert_small_kernel<<<1, blk, 0, stream>>>(d_in[7], d_in[8], d_in[9], d_in[10],
                                                qwb, kwb, vwb, gnwb, flagp);
    convert_t6_kernel<<<1088, blk, 0, stream>>>(d_in[1], d_in[2], d_in[3], d_in[4],
                                                d_in[5], d_in[6],
                                                WqkT, WkT, WvT, WsT, WgT, WoT, flagp);
    // v projection + transposing conv -> VT (d_out low half)
    gemm_mfma<0><<<dim3(8, 64), blk, 0, stream>>>(Xb, WvT, pre, nullptr, flagp, BT, VDn, Dn);
    conv_v_t_kernel<<<dim3(16, 32, 4), blk, 0, stream>>>(pre, vwb, VT);
    // merged q|k projection
    gemm_mfma<0><<<dim3(8, 64), blk, 0, stream>>>(Xb, WqkT, pre, nullptr, flagp, BT, 1024, Dn);
    // slot gates: ET (transposed) = exp(clip(X@Ws))
    gemm_mfma<2><<<dim3(2, 64), blk, 0, stream>>>(Xb, WsT, nullptr, ETb, flagp, BT, 256, Dn);
    // gate projection -> d_out high half (last use of Xb)
    gemm_mfma<0><<<dim3(8, 64), blk, 0, stream>>>(Xb, WgT, gate, nullptr, flagp, BT, VDn, Dn);
    // convs from pre (q natural, k transposed+rope)
    conv_q_kernel<<<8192, blk, 0, stream>>>(pre, qwb, Qb);
    conv_k_t_kernel<<<dim3(32, 4, 4), blk, 0, stream>>>(pre, kwb, KTb);
    // cumsum checkpoints + prefix-state scan (pre dead -> Svp region free)
    cumsum_ccp_kernel<<<256, blk, 0, stream>>>(ETb, Ccp);
    scan_state_kernel<<<96, blk, 0, stream>>>(ETb, KTb, VT, Svp, HpA, HpB);
    // fused attention + norm + gate -> OV (over dead Xb)
    attn12_mfma<<<dim3(16, 32), blk, 0, stream>>>(Qb, KTb, ETb, Ccp, HpA, HpB,
                                                  Svp, VT, gate, gnwb, OVb);
    // output projection
    gemm_mfma<3><<<dim3(8, 64), blk, 0, stream>>>(OVb, WoT, d_out, nullptr, flagp, BT, Dn, VDn);
}

// Round 10
// 425.196 us; speedup vs baseline: 1.1069x; 1.0487x over previous
//
#include <hip/hip_runtime.h>
#include <hip/hip_bf16.h>
#include <math.h>

typedef __hip_bfloat16 bf16;
typedef short s8v __attribute__((ext_vector_type(8)));
typedef short s4v __attribute__((ext_vector_type(4)));
typedef float f4v __attribute__((ext_vector_type(4)));

__device__ __forceinline__ float b2f(bf16 x) { return __bfloat162float(x); }
__device__ __forceinline__ bf16 f2b(float x) { return __float2bfloat16(x); }
__device__ __forceinline__ f4v mfma16(s8v a, s8v b, f4v c) {
    return __builtin_amdgcn_mfma_f32_16x16x32_bf16(a, b, c, 0, 0, 0);
}
__device__ __forceinline__ void async16(const bf16* g, bf16* l) {
    __builtin_amdgcn_global_load_lds(
        (const __attribute__((address_space(1))) void*)g,
        (__attribute__((address_space(3))) void*)l, 16, 0, 0);
}

constexpr int Bn = 4, Tn = 2048, Dn = 1024, KDn = 512, VDn = 1024;
constexpr int Hn = 4, Mn = 64, HKn = 128, HVn = 256;
constexpr int BT = Bn * Tn;

// ---------------------------------------------------------------------------
__global__ __launch_bounds__(256) void probe_dtype_kernel(
    const void* __restrict__ x, int* __restrict__ flag)
{
    const bf16* xb = (const bf16*)x;
    float mx = 0.f;
    for (int i = threadIdx.x; i < 4096; i += 256) {
        float v = fabsf(b2f(xb[i]));
        if (isnan(v)) v = 1e30f;
        mx = fmaxf(mx, v);
    }
    __shared__ float red[256];
    red[threadIdx.x] = mx;
    __syncthreads();
    for (int s = 128; s > 0; s >>= 1) {
        if (threadIdx.x < s) red[threadIdx.x] = fmaxf(red[threadIdx.x], red[threadIdx.x + s]);
        __syncthreads();
    }
    if (threadIdx.x == 0) flag[0] = (red[0] > 1e6f) ? 1 : 0;
}

__global__ __launch_bounds__(256) void convert_kernel(
    const void* __restrict__ src, bf16* __restrict__ dst,
    const int* __restrict__ flag, int n)
{
    int is32 = flag[0];
    int i0 = (blockIdx.x * 256 + threadIdx.x) * 4;
#pragma unroll
    for (int j = 0; j < 4; j++) {
        int i = i0 + j;
        if (i < n)
            dst[i] = is32 ? f2b(((const float*)src)[i]) : ((const bf16*)src)[i];
    }
}

__global__ __launch_bounds__(256) void convert_small_kernel(
    const void* __restrict__ q, const void* __restrict__ k,
    const void* __restrict__ v, const void* __restrict__ g,
    bf16* __restrict__ qd, bf16* __restrict__ kd,
    bf16* __restrict__ vd, bf16* __restrict__ gd,
    const int* __restrict__ flag)
{
    int is32 = flag[0];
    for (int i = threadIdx.x; i < 8448; i += 256) {
        const void* s; bf16* d; int l;
        if (i < 2048)      { s = q; d = qd; l = i; }
        else if (i < 4096) { s = k; d = kd; l = i - 2048; }
        else if (i < 8192) { s = v; d = vd; l = i - 4096; }
        else               { s = g; d = gd; l = i - 8192; }
        d[l] = is32 ? f2b(((const float*)s)[l]) : ((const bf16*)s)[l];
    }
}

__global__ __launch_bounds__(256) void convert_t6_kernel(
    const void* s0, const void* s1, const void* s2, const void* s3,
    const void* s4, const void* s5,
    bf16* d0, bf16* d1, bf16* d2, bf16* d3, bf16* d4, bf16* d5,
    const int* __restrict__ flag)
{
    __shared__ bf16 tile[64 * 72];
    int is32 = flag[0];
    int nb = blockIdx.x;
    const void* src; bf16* dst; int K, N, loc;
    if (nb < 128)       { src = s0; dst = d0; K = 1024; N = 512;  loc = nb; }
    else if (nb < 256)  { src = s1; dst = d1; K = 1024; N = 512;  loc = nb - 128; }
    else if (nb < 512)  { src = s2; dst = d2; K = 1024; N = 1024; loc = nb - 256; }
    else if (nb < 576)  { src = s3; dst = d3; K = 1024; N = 256;  loc = nb - 512; }
    else if (nb < 832)  { src = s4; dst = d4; K = 1024; N = 1024; loc = nb - 576; }
    else                { src = s5; dst = d5; K = 1024; N = 1024; loc = nb - 832; }
    int nt = N >> 6;
    int n0 = (loc % nt) * 64, k0 = (loc / nt) * 64;
    int tid = threadIdx.x;
    int r = tid >> 2, seg = (tid & 3) * 16;
#pragma unroll
    for (int i = 0; i < 16; i++) {
        size_t gi = (size_t)(k0 + r) * N + n0 + seg + i;
        float v = is32 ? ((const float*)src)[gi] : b2f(((const bf16*)src)[gi]);
        tile[r * 72 + seg + i] = f2b(v);
    }
    __syncthreads();
    bf16 tmp[16];
#pragma unroll
    for (int i = 0; i < 16; i++) tmp[i] = tile[(seg + i) * 72 + r];
    size_t o = (size_t)(n0 + r) * K + k0 + seg;
    *(s8v*)&dst[o] = *(s8v*)&tmp[0];
    *(s8v*)&dst[o + 8] = *(s8v*)&tmp[8];
}

// ---------------------------------------------------------------------------
// MFMA GEMM (m97 recipe). EP: 3 = dynamic fp32/bf16 per flag (final);
// EP 4 = merged projection: cols [0,1024) -> Cout (qk-pre, stride 1024),
// [1024,2048) -> aux1 (gate), [2048,3072) -> aux2 (v-pre),
// [3072,3328) -> Cout2 = transposed ET with exp(clip()) epilogue.
// ---------------------------------------------------------------------------
template <int EP>
__global__ __launch_bounds__(256) void gemm_mfma(
    const bf16* __restrict__ A, const bf16* __restrict__ BT,
    void* __restrict__ Cout, bf16* __restrict__ Cout2,
    bf16* __restrict__ aux1, bf16* __restrict__ aux2,
    const int* __restrict__ flag, int M, int N, int K)
{
    __shared__ bf16 Xs[128 * 64];
    __shared__ bf16 Ws2[128 * 64];
    const int tid = threadIdx.x;
    const int w = tid >> 6, lane = tid & 63;
    const int l16 = lane & 15, q = lane >> 4;
    const int wr = w >> 1, wc = w & 1;
    const int m0 = blockIdx.y * 128, n0 = blockIdx.x * 128;
    int dyn = 0;
    if (EP == 3) dyn = flag[0];

    const int srow = w * 32 + (lane >> 3);
    const int scol = (lane & 7) * 8;
    const bf16* ga = A + (size_t)(m0 + srow) * K + scol;
    const bf16* gb = BT + (size_t)(n0 + srow) * K + scol;

    f4v acc[4][4];
    f4v z = {0.f, 0.f, 0.f, 0.f};
#pragma unroll
    for (int i = 0; i < 4; i++)
#pragma unroll
        for (int j = 0; j < 4; j++) acc[i][j] = z;

    for (int k0 = 0; k0 < K; k0 += 64) {
#pragma unroll
        for (int c = 0; c < 4; c++) {
            async16(ga + (size_t)(c * 8) * K + k0, &Xs[(w * 32 + c * 8) * 64]);
            async16(gb + (size_t)(c * 8) * K + k0, &Ws2[(w * 32 + c * 8) * 64]);
        }
        __syncthreads();
#pragma unroll
        for (int kq = 0; kq < 2; kq++) {
            s8v a[4], b[4];
#pragma unroll
            for (int mi = 0; mi < 4; mi++)
                a[mi] = *(s8v*)&Xs[(wr * 64 + mi * 16 + l16) * 64 + kq * 32 + q * 8];
#pragma unroll
            for (int ni = 0; ni < 4; ni++)
                b[ni] = *(s8v*)&Ws2[(wc * 64 + ni * 16 + l16) * 64 + kq * 32 + q * 8];
#pragma unroll
            for (int mi = 0; mi < 4; mi++)
#pragma unroll
                for (int ni = 0; ni < 4; ni++)
                    acc[mi][ni] = mfma16(a[mi], b[ni], acc[mi][ni]);
        }
        __syncthreads();
    }
#pragma unroll
    for (int mi = 0; mi < 4; mi++)
#pragma unroll
        for (int ni = 0; ni < 4; ni++)
#pragma unroll
            for (int r = 0; r < 4; r++) {
                int row = m0 + wr * 64 + mi * 16 + q * 4 + r;
                int col = n0 + wc * 64 + ni * 16 + l16;
                float v = acc[mi][ni][r];
                if (EP == 4) {
                    if (col < 1024) {
                        ((bf16*)Cout)[(size_t)row * 1024 + col] = f2b(v);
                    } else if (col < 2048) {
                        aux1[(size_t)row * 1024 + (col - 1024)] = f2b(v);
                    } else if (col < 3072) {
                        aux2[(size_t)row * 1024 + (col - 2048)] = f2b(v);
                    } else {
                        float cl = fminf(32.f, fmaxf(-32.f, v));
                        bf16 e = f2b(expf(cl));
                        int b_ = row >> 11, t_ = row & 2047;
                        int c = col - 3072;
                        int h_ = c >> 6, m_ = c & 63;
                        Cout2[((size_t)((b_ * 4 + h_) * 64 + m_)) * 2048 + t_] = e;
                    }
                } else {  // EP == 3
                    size_t idx = (size_t)row * N + col;
                    if (dyn) ((float*)Cout)[idx] = v;
                    else ((bf16*)Cout)[idx] = f2b(v);
                }
            }
}

// ---------------------------------------------------------------------------
// conv+silu+rope for q only (pre row stride 1024, cols 0..511).
// ---------------------------------------------------------------------------
__global__ __launch_bounds__(256) void conv_q_kernel(
    const bf16* __restrict__ pre, const bf16* __restrict__ w,
    bf16* __restrict__ out)
{
    int gid = blockIdx.x * 256 + threadIdx.x;  // B*T*H*64
    int d = gid & 63;
    int h = (gid >> 6) & 3;
    int t = (gid >> 8) & 2047;
    int b = gid >> 19;
    int clo = h * HKn + d, chi = clo + 64;
    float ylo = 0.f, yhi = 0.f;
#pragma unroll
    for (int j = 0; j < 4; j++) {
        int tt = t - 3 + j;
        if (tt >= 0) {
            size_t rb = (size_t)(b * Tn + tt) * 1024;
            ylo += b2f(pre[rb + clo]) * b2f(w[clo * 4 + j]);
            yhi += b2f(pre[rb + chi]) * b2f(w[chi * 4 + j]);
        }
    }
    ylo = ylo / (1.f + expf(-ylo));
    yhi = yhi / (1.f + expf(-yhi));
    float invf = powf(10000.f, -(float)d * (1.f / 64.f));
    float th = (float)t * invf;
    float c = cosf(th), s = sinf(th);
    size_t rowbase = (size_t)(b * Tn + t) * KDn;
    out[rowbase + clo] = f2b(ylo * c - yhi * s);
    out[rowbase + chi] = f2b(yhi * c + ylo * s);
}

// ---------------------------------------------------------------------------
// conv+silu+rope for k, output TRANSPOSED: KT[(b*4+h)*128 + d][t].
// ---------------------------------------------------------------------------
__global__ __launch_bounds__(256) void conv_k_t_kernel(
    const bf16* __restrict__ pre, const bf16* __restrict__ w,
    bf16* __restrict__ KT)
{
    __shared__ bf16 tile[128 * 72];
    const int b = blockIdx.z, h = blockIdx.y, tt = blockIdx.x;
    const int tid = threadIdx.x;
    const int dp = tid >> 2, tq = tid & 3;
    const int clo = 512 + h * 128 + dp, chi = clo + 64;
    const float w0l = b2f(w[(h * 128 + dp) * 4 + 0]), w1l = b2f(w[(h * 128 + dp) * 4 + 1]),
                w2l = b2f(w[(h * 128 + dp) * 4 + 2]), w3l = b2f(w[(h * 128 + dp) * 4 + 3]);
    const float w0h = b2f(w[(h * 128 + dp + 64) * 4 + 0]), w1h = b2f(w[(h * 128 + dp + 64) * 4 + 1]),
                w2h = b2f(w[(h * 128 + dp + 64) * 4 + 2]), w3h = b2f(w[(h * 128 + dp + 64) * 4 + 3]);
    const float invf = powf(10000.f, -(float)dp * (1.f / 64.f));
    float l0 = 0.f, l1 = 0.f, l2 = 0.f, h0 = 0.f, h1 = 0.f, h2 = 0.f;
    int tg0 = tt * 64 + tq * 16;
#pragma unroll
    for (int p = 0; p < 3; p++) {
        int tg = tg0 - 3 + p;
        float xl = 0.f, xh = 0.f;
        if (tg >= 0) {
            size_t rb = (size_t)(b * Tn + tg) * 1024;
            xl = b2f(pre[rb + clo]);
            xh = b2f(pre[rb + chi]);
        }
        l0 = l1; l1 = l2; l2 = xl;
        h0 = h1; h1 = h2; h2 = xh;
    }
    for (int i = 0; i < 16; i++) {
        int tg = tg0 + i;
        size_t rb = (size_t)(b * Tn + tg) * 1024;
        float xl = b2f(pre[rb + clo]);
        float xh = b2f(pre[rb + chi]);
        float ylo = l0 * w0l + l1 * w1l + l2 * w2l + xl * w3l;
        float yhi = h0 * w0h + h1 * w1h + h2 * w2h + xh * w3h;
        l0 = l1; l1 = l2; l2 = xl;
        h0 = h1; h1 = h2; h2 = xh;
        ylo = ylo / (1.f + expf(-ylo));
        yhi = yhi / (1.f + expf(-yhi));
        float th = (float)tg * invf;
        float c = cosf(th), s = sinf(th);
        int tl = tq * 16 + i;
        tile[dp * 72 + tl] = f2b(ylo * c - yhi * s);
        tile[(dp + 64) * 72 + tl] = f2b(yhi * c + ylo * s);
    }
    __syncthreads();
#pragma unroll
    for (int c = 0; c < 4; c++) {
        int idx = c * 256 + tid;
        int ch = idx >> 3, t8 = (idx & 7) * 8;
        s8v v = *(s8v*)&tile[ch * 72 + t8];
        *(s8v*)&KT[((size_t)((b * 4 + h) * 128 + ch)) * 2048 + tt * 64 + t8] = v;
    }
}

// ---------------------------------------------------------------------------
// conv + silu for v -> VT[b*1024 + c][t].
// ---------------------------------------------------------------------------
__global__ __launch_bounds__(256) void conv_v_t_kernel(
    const bf16* __restrict__ pre, const bf16* __restrict__ w,
    bf16* __restrict__ VT)
{
    __shared__ bf16 tile[64 * 72];
    int c0 = blockIdx.x * 64, t0 = blockIdx.y * 64, b = blockIdx.z;
    int tid = threadIdx.x;
    int row = tid >> 2, seg = (tid & 3) * 16;
    float y[16];
#pragma unroll
    for (int i = 0; i < 16; i++) y[i] = 0.f;
#pragma unroll
    for (int j = 0; j < 4; j++) {
        int tt = t0 + row - 3 + j;
        if (tt >= 0) {
            const bf16* p = &pre[(size_t)(b * Tn + tt) * VDn + c0 + seg];
#pragma unroll
            for (int i = 0; i < 16; i++)
                y[i] += b2f(p[i]) * b2f(w[(c0 + seg + i) * 4 + j]);
        }
    }
#pragma unroll
    for (int i = 0; i < 16; i++) {
        float v = y[i] / (1.f + expf(-y[i]));
        tile[row * 72 + seg + i] = f2b(v);
    }
    __syncthreads();
    bf16 tmp[16];
#pragma unroll
    for (int i = 0; i < 16; i++) tmp[i] = tile[(seg + i) * 72 + row];
    size_t o = (size_t)(b * 1024 + c0 + row) * 2048 + t0 + seg;
    *(s8v*)&VT[o] = *(s8v*)&tmp[0];
    *(s8v*)&VT[o + 8] = *(s8v*)&tmp[8];
}

// ---------------------------------------------------------------------------
// cumsum checkpoints: Ccp[(b*32+j)*256 + hm] = sum of E over tiles < j.
// ---------------------------------------------------------------------------
__global__ __launch_bounds__(256) void cumsum_ccp_kernel(
    const bf16* __restrict__ ET, float* __restrict__ Ccp)
{
    int row = blockIdx.x * 4 + (threadIdx.x >> 6);   // 1024 rows = b*256 + hm
    int lane = threadIdx.x & 63;
    int b = row >> 8, hm = row & 255;
    const bf16* src = ET + (size_t)row * 2048;
    float run = 0.f;
    for (int ch = 0; ch < 32; ch++) {
        if (lane == 0) Ccp[(size_t)(b * 32 + ch) * 256 + hm] = run;
        float v = b2f(src[ch * 64 + lane]);
#pragma unroll
        for (int off = 1; off < 64; off <<= 1) {
            float o = __shfl_up(v, off, 64);
            if (lane >= off) v += o;
        }
        run += __shfl(v, 63, 64);
    }
}

// ---------------------------------------------------------------------------
// Phase A: per-tile state products (independent blocks, high occupancy).
// blocks [0,512): Sv tiles Tv_j[v=256][m=64] = V_j^T E_j  (bh = bx>>5, j = bx&31)
// blocks [512,1024): H tiles Th_j[m=64][k=128] = E_j^T K_j
// ---------------------------------------------------------------------------
__global__ __launch_bounds__(256) void tile_state_kernel(
    const bf16* __restrict__ ET, const bf16* __restrict__ KT,
    const bf16* __restrict__ VT,
    bf16* __restrict__ Svp, bf16* __restrict__ HpA, bf16* __restrict__ HpB)
{
    const int tid = threadIdx.x;
    const int w = tid >> 6, lane = tid & 63;
    const int l16 = lane & 15, q = lane >> 4;
    f4v z = {0.f, 0.f, 0.f, 0.f};
    if (blockIdx.x < 512) {
        const int bh = blockIdx.x >> 5, j = blockIdx.x & 31;
        const int b = bh >> 2, h = bh & 3;
        const int j64 = j * 64;
        f4v acc[4][4];
#pragma unroll
        for (int i = 0; i < 4; i++)
#pragma unroll
            for (int jj = 0; jj < 4; jj++) acc[i][jj] = z;
#pragma unroll
        for (int kc = 0; kc < 2; kc++) {
            s8v va[4], eb[4];
#pragma unroll
            for (int vf = 0; vf < 4; vf++)
                va[vf] = *(const s8v*)(VT + (size_t)(b * 1024 + h * 256 + w * 64 + vf * 16 + l16) * 2048
                                       + j64 + kc * 32 + q * 8);
#pragma unroll
            for (int mf = 0; mf < 4; mf++)
                eb[mf] = *(const s8v*)(ET + (size_t)(bh * 64 + mf * 16 + l16) * 2048
                                       + j64 + kc * 32 + q * 8);
#pragma unroll
            for (int vf = 0; vf < 4; vf++)
#pragma unroll
                for (int mf = 0; mf < 4; mf++)
                    acc[vf][mf] = mfma16(va[vf], eb[mf], acc[vf][mf]);
        }
#pragma unroll
        for (int vf = 0; vf < 4; vf++)
#pragma unroll
            for (int mf = 0; mf < 4; mf++)
#pragma unroll
                for (int r = 0; r < 4; r++)
                    Svp[((size_t)((bh * 32 + j) * 256 + w * 64 + vf * 16 + q * 4 + r)) * 64
                        + mf * 16 + l16] = f2b(acc[vf][mf][r]);
    } else {
        const int idx = blockIdx.x - 512;
        const int bh = idx >> 5, j = idx & 31;
        const int j64 = j * 64;
        bf16* hp = (bh < 12) ? (HpA + (size_t)bh * 262144)
                             : (HpB + (size_t)(bh - 12) * 262144);
        f4v acc[8];
#pragma unroll
        for (int i = 0; i < 8; i++) acc[i] = z;
#pragma unroll
        for (int kc = 0; kc < 2; kc++) {
            s8v ea = *(const s8v*)(ET + (size_t)(bh * 64 + w * 16 + l16) * 2048
                                   + j64 + kc * 32 + q * 8);
#pragma unroll
            for (int kf = 0; kf < 8; kf++) {
                s8v kb = *(const s8v*)(KT + (size_t)(bh * 128 + kf * 16 + l16) * 2048
                                       + j64 + kc * 32 + q * 8);
                acc[kf] = mfma16(ea, kb, acc[kf]);
            }
        }
#pragma unroll
        for (int kf = 0; kf < 8; kf++)
#pragma unroll
            for (int r = 0; r < 4; r++)
                hp[((size_t)(j64 + w * 16 + q * 4 + r)) * 128 + kf * 16 + l16]
                    = f2b(acc[kf][r]);
    }
}

// ---------------------------------------------------------------------------
// Phase B: in-place exclusive prefix over j (fp32 accumulation, bf16 storage).
// blocks [0,1024): Sv (thread per (bh, v*64+m)); [1024,1536): H (per (bh, m*128+k)).
// ---------------------------------------------------------------------------
__global__ __launch_bounds__(256) void prefix_state_kernel(
    bf16* __restrict__ Svp, bf16* __restrict__ HpA, bf16* __restrict__ HpB)
{
    if (blockIdx.x < 1024) {
        int gid = blockIdx.x * 256 + threadIdx.x;
        int bh = gid >> 14, e = gid & 16383;
        bf16* p = Svp + (size_t)bh * 524288 + e;
        float run = 0.f;
#pragma unroll 4
        for (int j = 0; j < 32; j++) {
            float x = b2f(p[(size_t)j * 16384]);
            p[(size_t)j * 16384] = f2b(run);
            run += x;
        }
    } else {
        int gid = (blockIdx.x - 1024) * 256 + threadIdx.x;
        int bh = gid >> 13, e = gid & 8191;
        bf16* hp = ((bh < 12) ? (HpA + (size_t)bh * 262144)
                              : (HpB + (size_t)(bh - 12) * 262144)) + e;
        float run = 0.f;
#pragma unroll 4
        for (int j = 0; j < 32; j++) {
            float x = b2f(hp[(size_t)j * 8192]);
            hp[(size_t)j * 8192] = f2b(run);
            run += x;
        }
    }
}

// ---------------------------------------------------------------------------
// Fused attention (unchanged from round 9).
// ---------------------------------------------------------------------------
__global__ __launch_bounds__(256) void attn12_mfma(
    const bf16* __restrict__ Q, const bf16* __restrict__ KT,
    const bf16* __restrict__ ET, const float* __restrict__ Ccp,
    const bf16* __restrict__ HpA, const bf16* __restrict__ HpB,
    const bf16* __restrict__ Svp, const bf16* __restrict__ VT,
    const bf16* __restrict__ gate, const bf16* __restrict__ gn,
    bf16* __restrict__ OV)
{
    __shared__ char smem[53760];
    bf16*  Kloc = (bf16*)smem;
    float* Ot   = (float*)smem;
    bf16*  Sl   = (bf16*)(smem + 17408);
    bf16*  Ct   = (bf16*)(smem + 17408);
    bf16*  Etl  = (bf16*)(smem + 17408);
    float* okT  = (float*)(smem + 26624);
    bf16*  Pl   = (bf16*)(smem + 26624);
    bf16*  Ul   = (bf16*)(smem + 43264);
    float* swave= (float*)(smem + 52480);
    float* ssum = (float*)(smem + 53504);
    const int tid = threadIdx.x;
    const int w = tid >> 6, lane = tid & 63;
    const int l16 = lane & 15, q = lane >> 4;
    const int bh = blockIdx.x, b = bh >> 2, h = bh & 3;
    const int j = blockIdx.y, j64 = j * 64;
    f4v z = {0.f, 0.f, 0.f, 0.f};
    const bf16* hp = (bh < 12) ? (HpA + (size_t)bh * 262144)
                               : (HpB + (size_t)(bh - 12) * 262144);

#pragma unroll
    for (int c = 0; c < 4; c++) {
        int idx = c * 256 + tid;
        int kr = idx >> 3, t8 = (idx & 7) * 8;
        alignas(16) bf16 tmp[8];
        *(s8v*)tmp = *(const s8v*)&KT[((size_t)(bh * 128 + kr)) * 2048 + j64 + t8];
#pragma unroll
        for (int i = 0; i < 8; i++) Kloc[(t8 + i) * 136 + kr] = tmp[i];
    }
    const bf16* qrow = Q + (size_t)(b * 2048 + j64 + w * 16 + l16) * 512 + h * 128;
    s8v qa[4];
#pragma unroll
    for (int kc = 0; kc < 4; kc++) qa[kc] = *(const s8v*)(qrow + kc * 32 + q * 8);
    __syncthreads();
    {
        f4v sT[4];
#pragma unroll
        for (int fi = 0; fi < 4; fi++) sT[fi] = z;
#pragma unroll
        for (int kc = 0; kc < 4; kc++)
#pragma unroll
            for (int fi = 0; fi < 4; fi++) {
                s8v kb = *(s8v*)&Kloc[(fi * 16 + l16) * 136 + kc * 32 + q * 8];
                sT[fi] = mfma16(kb, qa[kc], sT[fi]);
            }
        const int tl = w * 16 + l16;
#pragma unroll
        for (int fi = 0; fi < 4; fi++) {
            alignas(8) bf16 pk[4];
#pragma unroll
            for (int r = 0; r < 4; r++) {
                int taul = fi * 16 + q * 4 + r;
                pk[r] = (taul <= tl) ? f2b(sT[fi][r]) : f2b(0.f);
            }
            *(s4v*)&Sl[tl * 72 + fi * 16 + q * 4] = *(s4v*)pk;
        }
    }
    __syncthreads();
    {
        f4v ok[4];
#pragma unroll
        for (int i = 0; i < 4; i++) ok[i] = z;
        const bf16* etrow = ET + (size_t)(bh * 64 + w * 16 + l16) * 2048 + j64;
#pragma unroll
        for (int kc = 0; kc < 2; kc++) {
            s8v ea = *(const s8v*)(etrow + kc * 32 + q * 8);
#pragma unroll
            for (int tf = 0; tf < 4; tf++) {
                s8v sb = *(s8v*)&Sl[(tf * 16 + l16) * 72 + kc * 32 + q * 8];
                ok[tf] = mfma16(ea, sb, ok[tf]);
            }
        }
        const bf16* hrow = hp + (size_t)(j64 + w * 16 + l16) * 128;
#pragma unroll
        for (int kc = 0; kc < 4; kc++) {
            s8v ha = *(const s8v*)(hrow + kc * 32 + q * 8);
#pragma unroll
            for (int tf = 0; tf < 4; tf++) {
                s8v qb = *(const s8v*)(Q + (size_t)(b * 2048 + j64 + tf * 16 + l16) * 512
                                       + h * 128 + kc * 32 + q * 8);
                ok[tf] = mfma16(ha, qb, ok[tf]);
            }
        }
#pragma unroll
        for (int tf = 0; tf < 4; tf++)
#pragma unroll
            for (int r = 0; r < 4; r++)
                okT[(w * 16 + q * 4 + r) * 65 + tf * 16 + l16] = ok[tf][r];
    }
    __syncthreads();
    for (int mi = 0; mi < 16; mi++) {
        int m = w * 16 + mi;
        float v = b2f(ET[(size_t)(bh * 64 + m) * 2048 + j64 + lane]);
#pragma unroll
        for (int off = 1; off < 64; off <<= 1) {
            float o = __shfl_up(v, off, 64);
            if (lane >= off) v += o;
        }
        float c0 = Ccp[(size_t)(b * 32 + j) * 256 + h * 64 + m];
        Ct[m * 72 + lane] = f2b(c0 + v);
    }
    __syncthreads();
    if (tid < 64) {
        const int t = tid;
        const float scale = 0.08838834764831845f;
        float mx = -1e30f;
        for (int m = 0; m < 64; m++) {
            float c = b2f(Ct[m * 72 + t]);
            float v = okT[m * 65 + t] * scale / c;
            okT[m * 65 + t] = v;
            mx = fmaxf(mx, v);
        }
        float sum = 0.f;
        for (int m = 0; m < 64; m++) {
            float e = expf(okT[m * 65 + t] - mx);
            okT[m * 65 + t] = e;
            sum += e;
        }
        float inv = 1.f / sum;
        for (int m = 0; m < 64; m++) {
            float c = b2f(Ct[m * 72 + t]);
            Ul[t * 72 + m] = f2b(okT[m * 65 + t] * inv / c);
        }
    }
    __syncthreads();
#pragma unroll
    for (int c = 0; c < 2; c++) {
        int idx = c * 256 + tid;
        int mr = idx >> 3, t8 = (idx & 7) * 8;
        alignas(16) bf16 tmp[8];
        *(s8v*)tmp = *(const s8v*)&ET[(size_t)(bh * 64 + mr) * 2048 + j64 + t8];
#pragma unroll
        for (int i = 0; i < 8; i++) Etl[(t8 + i) * 72 + mr] = tmp[i];
    }
    __syncthreads();
    {
        s8v ub[2];
#pragma unroll
        for (int kc = 0; kc < 2; kc++)
            ub[kc] = *(s8v*)&Ul[(w * 16 + l16) * 72 + kc * 32 + q * 8];
        f4v pT[4];
#pragma unroll
        for (int fi = 0; fi < 4; fi++) pT[fi] = z;
#pragma unroll
        for (int kc = 0; kc < 2; kc++)
#pragma unroll
            for (int fi = 0; fi < 4; fi++) {
                s8v eb = *(s8v*)&Etl[(fi * 16 + l16) * 72 + kc * 32 + q * 8];
                pT[fi] = mfma16(eb, ub[kc], pT[fi]);
            }
        const int tl = w * 16 + l16;
#pragma unroll
        for (int fi = 0; fi < 4; fi++) {
            alignas(8) bf16 pk[4];
#pragma unroll
            for (int r = 0; r < 4; r++) {
                int taul = fi * 16 + q * 4 + r;
                pk[r] = (taul <= tl) ? f2b(pT[fi][r]) : f2b(0.f);
            }
            *(s4v*)&Pl[tl * 72 + fi * 16 + q * 4] = *(s4v*)pk;
        }
    }
    __syncthreads();
    f4v oacc[4][4];
#pragma unroll
    for (int zc = 0; zc < 4; zc++)
#pragma unroll
        for (int i = 0; i < 4; i++) oacc[zc][i] = z;
    {
        const bf16* vtrow = VT + (size_t)(b * 1024 + h * 256 + w * 16 + l16) * 2048 + j64;
        const bf16* svrow = Svp + (size_t)((bh * 32 + j) * 256 + w * 16 + l16) * 64;
#pragma unroll
        for (int kc = 0; kc < 2; kc++) {
            s8v pb[4], ub2[4];
#pragma unroll
            for (int tf = 0; tf < 4; tf++) {
                pb[tf] = *(s8v*)&Pl[(tf * 16 + l16) * 72 + kc * 32 + q * 8];
                ub2[tf] = *(s8v*)&Ul[(tf * 16 + l16) * 72 + kc * 32 + q * 8];
            }
#pragma unroll
            for (int zc = 0; zc < 4; zc++) {
                s8v vt = *(const s8v*)(vtrow + (size_t)(zc * 64) * 2048 + kc * 32 + q * 8);
                s8v sv = *(const s8v*)(svrow + (size_t)(zc * 64) * 64 + kc * 32 + q * 8);
#pragma unroll
                for (int tf = 0; tf < 4; tf++) {
                    oacc[zc][tf] = mfma16(vt, pb[tf], oacc[zc][tf]);
                    oacc[zc][tf] = mfma16(sv, ub2[tf], oacc[zc][tf]);
                }
            }
        }
    }
    float part[4] = {0.f, 0.f, 0.f, 0.f};
#pragma unroll
    for (int zc = 0; zc < 4; zc++)
#pragma unroll
        for (int tf = 0; tf < 4; tf++)
#pragma unroll
            for (int r = 0; r < 4; r++)
                part[tf] += oacc[zc][tf][r] * oacc[zc][tf][r];
#pragma unroll
    for (int tf = 0; tf < 4; tf++) {
        part[tf] += __shfl_xor(part[tf], 16, 64);
        part[tf] += __shfl_xor(part[tf], 32, 64);
    }
    if (q == 0) {
#pragma unroll
        for (int tf = 0; tf < 4; tf++) swave[w * 64 + tf * 16 + l16] = part[tf];
    }
    const int trow = tid >> 2, vseg = (tid & 3) * 16;
    for (int zc = 0; zc < 4; zc++) {
#pragma unroll
        for (int tf = 0; tf < 4; tf++)
            *(f4v*)&Ot[(tf * 16 + l16) * 68 + w * 16 + q * 4] = oacc[zc][tf];
        __syncthreads();
        if (zc == 0) {
            if (tid < 64)
                ssum[tid] = rsqrtf((swave[tid] + swave[64 + tid] + swave[128 + tid]
                                    + swave[192 + tid]) * (1.0f / 256.0f) + 1e-5f);
            __syncthreads();
        }
        float rs = ssum[trow];
        size_t orow = (size_t)(b * 2048 + j64 + trow) * 1024 + h * 256 + zc * 64 + vseg;
        alignas(16) bf16 gh[16];
        *(s8v*)&gh[0] = *(const s8v*)&gate[orow];
        *(s8v*)&gh[8] = *(const s8v*)&gate[orow + 8];
        alignas(16) bf16 tmp[16];
#pragma unroll
        for (int i = 0; i < 16; i++) {
            float g = b2f(gh[i]);
            float sg = g / (1.f + expf(-g));
            float val = Ot[trow * 68 + vseg + i] * rs * b2f(gn[zc * 64 + vseg + i]) * sg;
            tmp[i] = f2b(val);
        }
        *(s8v*)&OV[orow] = *(s8v*)&tmp[0];
        *(s8v*)&OV[orow + 8] = *(s8v*)&tmp[8];
        __syncthreads();
    }
}

// ---------------------------------------------------------------------------
extern "C" void kernel_launch(void* const* d_in, const int* in_sizes, int n_in,
                              void* d_out, int out_size, void* d_ws, size_t ws_size,
                              hipStream_t stream)
{
    constexpr size_t MB = 1u << 20;
    char* w = (char*)d_ws;
    bf16* Xb   = (bf16*)(w + 0);                 // [0,16) -> OV after merged GEMM
    bf16* OVb  = (bf16*)(w + 0);
    bf16* WoT  = (bf16*)(w + 16 * MB);           // [16,18)
    bf16* WallT= (bf16*)(w + 18 * MB);           // [18,24.5): WqkT|WgT|WvT|WsT
    bf16* WkT  = (bf16*)(w + 19 * MB);
    bf16* WgT  = (bf16*)(w + 20 * MB);
    bf16* WvT  = (bf16*)(w + 22 * MB);
    bf16* WsT  = (bf16*)(w + 24 * MB);
    bf16* HpA  = (bf16*)(w + 18 * MB);           // [18,24) after merged GEMM
    bf16* gnwb = (bf16*)(w + 24 * MB + 524288);  // smalls [24.5,25)
    bf16* qwb  = (bf16*)(w + 24 * MB + 532480);
    bf16* kwb  = (bf16*)(w + 24 * MB + 540672);
    bf16* vwb  = (bf16*)(w + 24 * MB + 548864);
    int*  flagp= (int*) (w + 24 * MB + 565248);
    bf16* qkpre= (bf16*)(w + 25 * MB);           // [25,41) -> Svp after convs
    bf16* Svp  = (bf16*)(w + 25 * MB);
    bf16* ETb  = (bf16*)(w + 41 * MB);           // [41,45)
    bf16* vpre = (bf16*)(w + 45 * MB);           // [45,61) -> Qb/KTb after conv_v
    bf16* Qb   = (bf16*)(w + 45 * MB);           // [45,53)
    bf16* KTb  = (bf16*)(w + 53 * MB);           // [53,61)
    float* Ccp = (float*)(w + 61 * MB);          // [61,61.25)
    bf16* HpB  = (bf16*)(w + 61 * MB + 262144);  // [61.25,63.25)
    bf16* VT   = (bf16*)d_out;                   // d_out[0,16MB)
    bf16* gate = (bf16*)d_out + 8 * 1024 * 1024; // d_out[16,32MB)

    dim3 blk(256);
    probe_dtype_kernel<<<1, blk, 0, stream>>>(d_in[0], flagp);
    convert_kernel<<<16384, blk, 0, stream>>>(d_in[0], Xb, flagp, BT * Dn);
    convert_small_kernel<<<1, blk, 0, stream>>>(d_in[7], d_in[8], d_in[9], d_in[10],
                                                qwb, kwb, vwb, gnwb, flagp);
    convert_t6_kernel<<<1088, blk, 0, stream>>>(d_in[1], d_in[2], d_in[3], d_in[4],
                                                d_in[5], d_in[6],
                                                WallT, WkT, WvT, WsT, WgT, WoT, flagp);
    // ONE merged projection GEMM: N = 3328 (qk | gate | v | s->ET)
    gemm_mfma<4><<<dim3(26, 64), blk, 0, stream>>>(Xb, WallT, qkpre, ETb, gate, vpre,
                                                   flagp, BT, 3328, Dn);
    // convs: v (transposed), q, k (transposed+rope)
    conv_v_t_kernel<<<dim3(16, 32, 4), blk, 0, stream>>>(vpre, vwb, VT);
    conv_q_kernel<<<8192, blk, 0, stream>>>(qkpre, qwb, Qb);
    conv_k_t_kernel<<<dim3(32, 4, 4), blk, 0, stream>>>(qkpre, kwb, KTb);
    // per-slot scalar checkpoints
    cumsum_ccp_kernel<<<256, blk, 0, stream>>>(ETb, Ccp);
    // two-phase prefix state: independent tile products, then prefix pass
    tile_state_kernel<<<1024, blk, 0, stream>>>(ETb, KTb, VT, Svp, HpA, HpB);
    prefix_state_kernel<<<1536, blk, 0, stream>>>(Svp, HpA, HpB);
    // fused attention + norm + gate -> OV (over dead Xb)
    attn12_mfma<<<dim3(16, 32), blk, 0, stream>>>(Qb, KTb, ETb, Ccp, HpA, HpB,
                                                  Svp, VT, gate, gnwb, OVb);
    // output projection (dynamic out dtype)
    gemm_mfma<3><<<dim3(8, 64), blk, 0, stream>>>(OVb, WoT, d_out, nullptr, nullptr, nullptr,
                                                  flagp, BT, Dn, VDn);
}